// Round 1
// baseline (5712.934 us; speedup 1.0000x reference)
//
#include <hip/hip_runtime.h>

#define NNODES 100000
#define NEDGES 1600000
#define INSIZE 128
#define HIDDEN 128
#define OUTSIZE 64

// ---------------------------------------------------------------------------
// Scatter-add of source-node features into neigh[dst]. One edge is handled by
// 32 consecutive threads (c = 0..31), each doing one float4 (128 floats/row).
// Reads are coalesced (512B per edge per 32 lanes); writes are fp32 atomics.
// Optionally accumulates in-degree (layer 1 only).
// ---------------------------------------------------------------------------
__global__ void scatter_edges(const float4* __restrict__ x,   // [NNODES, 32] as float4
                              const int* __restrict__ src,
                              const int* __restrict__ dst,
                              float* __restrict__ neigh,      // [NNODES, 128]
                              float* __restrict__ deg)        // nullptr for layer 2
{
    long gid = (long)blockIdx.x * blockDim.x + threadIdx.x;
    int e = (int)(gid >> 5);
    int c = (int)(gid & 31);
    if (e >= NEDGES) return;
    int s = src[e];
    int d = dst[e];
    float4 v = x[(long)s * 32 + c];
    float* p = neigh + (long)d * 128 + c * 4;
    atomicAdd(p + 0, v.x);
    atomicAdd(p + 1, v.y);
    atomicAdd(p + 2, v.z);
    atomicAdd(p + 3, v.w);
    if (deg != nullptr && c == 0) {
        atomicAdd(deg + d, 1.0f);
    }
}

// ---------------------------------------------------------------------------
// Fused normalize + GEMM + bias (+ relu):
//   out[n][j] = act( ((neigh[n]+self[n]) / (deg[n]+1)) . W[:,j] + b[j] )
// Block = NOUT threads (one thread per output column), NPB nodes per block.
// Normalized input rows staged in LDS; W reads coalesced across j and reused
// across the NPB nodes.
// ---------------------------------------------------------------------------
template <int NOUT, int NPB, bool RELU>
__global__ void sage_gemm(const float* __restrict__ neigh,  // [NNODES, 128]
                          const float* __restrict__ self,   // [NNODES, 128]
                          const float* __restrict__ deg,    // [NNODES]
                          const float* __restrict__ W,      // [128, NOUT]
                          const float* __restrict__ b,      // [NOUT]
                          float* __restrict__ out)          // [NNODES, NOUT]
{
    __shared__ float xs[NPB][129];  // +1 pad
    int node0 = blockIdx.x * NPB;
    int tid = threadIdx.x;

    // Cooperative load + normalize of NPB input rows.
    for (int i = tid; i < NPB * 128; i += NOUT) {
        int n = i >> 7;
        int k = i & 127;
        int node = node0 + n;
        float val = 0.0f;
        if (node < NNODES) {
            float inv = 1.0f / (deg[node] + 1.0f);
            val = (neigh[(long)node * 128 + k] + self[(long)node * 128 + k]) * inv;
        }
        xs[n][k] = val;
    }
    __syncthreads();

    float acc[NPB];
#pragma unroll
    for (int n = 0; n < NPB; n++) acc[n] = 0.0f;

    int j = tid;
    for (int k = 0; k < 128; k++) {
        float wv = W[k * NOUT + j];  // coalesced across j
#pragma unroll
        for (int n = 0; n < NPB; n++) {
            acc[n] += xs[n][k] * wv;  // LDS broadcast (same addr all lanes)
        }
    }

    float bj = b[j];
#pragma unroll
    for (int n = 0; n < NPB; n++) {
        int node = node0 + n;
        if (node < NNODES) {
            float o = acc[n] + bj;
            if (RELU) o = fmaxf(o, 0.0f);
            out[(long)node * NOUT + j] = o;
        }
    }
}

extern "C" void kernel_launch(void* const* d_in, const int* in_sizes, int n_in,
                              void* d_out, int out_size, void* d_ws, size_t ws_size,
                              hipStream_t stream) {
    const float* feat = (const float*)d_in[0];  // [100000, 128]
    const float* W1   = (const float*)d_in[1];  // [128, 128]
    const float* b1   = (const float*)d_in[2];  // [128]
    const float* W2   = (const float*)d_in[3];  // [128, 64]
    const float* b2   = (const float*)d_in[4];  // [64]
    const int*   src  = (const int*)d_in[5];    // [1600000]
    const int*   dst  = (const int*)d_in[6];    // [1600000]
    float* out = (float*)d_out;                 // [100000, 64]

    // Workspace layout (all offsets 256B-aligned):
    //   deg   : 100000 f32           @ 0          (400,000 B)
    //   neigh : 100000*128 f32       @ 524,288    (51,200,000 B) -- reused both layers
    //   h1    : 100000*128 f32       @ 51,724,288 (51,200,000 B)
    // total: 102,924,288 B
    char* ws = (char*)d_ws;
    float* deg   = (float*)(ws);
    float* neigh = (float*)(ws + 524288);
    float* h1    = (float*)(ws + 51724288);

    const size_t neigh_bytes = (size_t)NNODES * 128 * sizeof(float);

    // ---- Layer 1 ----
    hipMemsetAsync(deg, 0, (size_t)NNODES * sizeof(float), stream);
    hipMemsetAsync(neigh, 0, neigh_bytes, stream);

    {
        long total = (long)NEDGES * 32;
        int blocks = (int)((total + 255) / 256);
        scatter_edges<<<blocks, 256, 0, stream>>>((const float4*)feat, src, dst,
                                                  neigh, deg);
    }
    {
        const int NPB = 8;
        int blocks = (NNODES + NPB - 1) / NPB;
        sage_gemm<HIDDEN, NPB, true><<<blocks, HIDDEN, 0, stream>>>(
            neigh, feat, deg, W1, b1, h1);
    }

    // ---- Layer 2 ----
    hipMemsetAsync(neigh, 0, neigh_bytes, stream);
    {
        long total = (long)NEDGES * 32;
        int blocks = (int)((total + 255) / 256);
        scatter_edges<<<blocks, 256, 0, stream>>>((const float4*)h1, src, dst,
                                                  neigh, nullptr);
    }
    {
        const int NPB = 16;
        int blocks = (NNODES + NPB - 1) / NPB;
        sage_gemm<OUTSIZE, NPB, false><<<blocks, OUTSIZE, 0, stream>>>(
            neigh, h1, deg, W2, b2, out);
    }
}

// Round 2
// 751.880 us; speedup vs baseline: 7.5982x; 7.5982x over previous
//
#include <hip/hip_runtime.h>

#define NNODES 100000
#define NEDGES 1600000
#define INSIZE 128
#define HIDDEN 128
#define OUTSIZE 64

// ---------------------------------------------------------------------------
// CSR build: histogram -> exclusive scan (3 kernels) -> fill.
// ---------------------------------------------------------------------------
__global__ void hist_kernel(const int* __restrict__ dst, int* __restrict__ counts) {
    int e = blockIdx.x * blockDim.x + threadIdx.x;
    if (e < NEDGES) atomicAdd(&counts[dst[e]], 1);
}

// 1024 elements per block (256 threads x 4), block-local exclusive scan.
__global__ void scan_block(const int* __restrict__ counts, int* __restrict__ offs,
                           int* __restrict__ bsums) {
    __shared__ int s[256];
    int tid = threadIdx.x;
    int base = blockIdx.x * 1024 + tid * 4;
    int v0 = (base + 0 < NNODES) ? counts[base + 0] : 0;
    int v1 = (base + 1 < NNODES) ? counts[base + 1] : 0;
    int v2 = (base + 2 < NNODES) ? counts[base + 2] : 0;
    int v3 = (base + 3 < NNODES) ? counts[base + 3] : 0;
    int tsum = v0 + v1 + v2 + v3;
    s[tid] = tsum;
    __syncthreads();
    for (int off = 1; off < 256; off <<= 1) {
        int t = (tid >= off) ? s[tid - off] : 0;
        __syncthreads();
        s[tid] += t;
        __syncthreads();
    }
    int excl = s[tid] - tsum;  // exclusive prefix of this thread's group
    if (base + 0 < NNODES) offs[base + 0] = excl;
    if (base + 1 < NNODES) offs[base + 1] = excl + v0;
    if (base + 2 < NNODES) offs[base + 2] = excl + v0 + v1;
    if (base + 3 < NNODES) offs[base + 3] = excl + v0 + v1 + v2;
    if (tid == 255) bsums[blockIdx.x] = s[255];
}

// Serial exclusive scan of the (<=128) block sums; writes total to offs[NNODES].
__global__ void scan_sums(int* __restrict__ bsums, int* __restrict__ offs, int nblocks) {
    int run = 0;
    for (int i = 0; i < nblocks; i++) {
        int t = bsums[i];
        bsums[i] = run;
        run += t;
    }
    offs[NNODES] = run;  // == NEDGES
}

__global__ void scan_add(int* __restrict__ offs, const int* __restrict__ bsums) {
    int base = blockIdx.x * 1024 + threadIdx.x * 4;
    int add = bsums[blockIdx.x];
    if (base + 0 < NNODES) offs[base + 0] += add;
    if (base + 1 < NNODES) offs[base + 1] += add;
    if (base + 2 < NNODES) offs[base + 2] += add;
    if (base + 3 < NNODES) offs[base + 3] += add;
}

__global__ void fill_kernel(const int* __restrict__ src, const int* __restrict__ dst,
                            const int* __restrict__ offs, int* __restrict__ cursor,
                            int* __restrict__ csr_src) {
    int e = blockIdx.x * blockDim.x + threadIdx.x;
    if (e >= NEDGES) return;
    int d = dst[e];
    int slot = atomicAdd(&cursor[d], 1);
    csr_src[offs[d] + slot] = src[e];
}

// ---------------------------------------------------------------------------
// Gather + normalize: one wave (64 lanes) per destination node; each lane owns
// a float2 (128 floats/row). Per edge: one uniform index load (broadcast) +
// one fully-coalesced 512B row read. Output is the normalized h_neigh:
//   out[n] = (sum_{e in in(n)} x[src[e]] + x[n]) / (deg(n) + 1)
// ---------------------------------------------------------------------------
__global__ void gather_kernel(const float2* __restrict__ x,      // [NNODES*64]
                              const int* __restrict__ offs,
                              const int* __restrict__ csr_src,
                              float2* __restrict__ outx)         // [NNODES*64]
{
    int wid = (int)((blockIdx.x * (long)blockDim.x + threadIdx.x) >> 6);  // node
    int lane = threadIdx.x & 63;
    if (wid >= NNODES) return;
    int beg = offs[wid];
    int end = offs[wid + 1];
    float2 acc = x[(long)wid * 64 + lane];  // self term
    for (int e = beg; e < end; e++) {
        int s = csr_src[e];
        float2 v = x[(long)s * 64 + lane];
        acc.x += v.x;
        acc.y += v.y;
    }
    float inv = 1.0f / (float)(end - beg + 1);
    acc.x *= inv;
    acc.y *= inv;
    outx[(long)wid * 64 + lane] = acc;
}

// ---------------------------------------------------------------------------
// GEMM + bias (+ relu) on pre-normalized input:
//   out[n][j] = act( hin[n] . W[:,j] + b[j] )
// Block = NOUT threads (one per output column), NPB nodes per block; input rows
// staged in LDS, W reads coalesced across j and reused across NPB nodes.
// ---------------------------------------------------------------------------
template <int NOUT, int NPB, bool RELU>
__global__ void sage_gemm(const float* __restrict__ hin,  // [NNODES, 128]
                          const float* __restrict__ W,    // [128, NOUT]
                          const float* __restrict__ b,    // [NOUT]
                          float* __restrict__ out)        // [NNODES, NOUT]
{
    __shared__ float xs[NPB][129];  // +1 pad
    int node0 = blockIdx.x * NPB;
    int tid = threadIdx.x;

    const float4* h4 = (const float4*)hin;
    for (int i = tid; i < NPB * 32; i += NOUT) {
        int n = i >> 5;
        int k = i & 31;
        int node = node0 + n;
        float4 v = make_float4(0.f, 0.f, 0.f, 0.f);
        if (node < NNODES) v = h4[(long)node * 32 + k];
        xs[n][k * 4 + 0] = v.x;
        xs[n][k * 4 + 1] = v.y;
        xs[n][k * 4 + 2] = v.z;
        xs[n][k * 4 + 3] = v.w;
    }
    __syncthreads();

    float acc[NPB];
#pragma unroll
    for (int n = 0; n < NPB; n++) acc[n] = 0.0f;

    int j = tid;
    for (int k = 0; k < 128; k++) {
        float wv = W[k * NOUT + j];  // coalesced across j
#pragma unroll
        for (int n = 0; n < NPB; n++) {
            acc[n] += xs[n][k] * wv;  // LDS broadcast
        }
    }

    float bj = b[j];
#pragma unroll
    for (int n = 0; n < NPB; n++) {
        int node = node0 + n;
        if (node < NNODES) {
            float o = acc[n] + bj;
            if (RELU) o = fmaxf(o, 0.0f);
            out[(long)node * NOUT + j] = o;
        }
    }
}

extern "C" void kernel_launch(void* const* d_in, const int* in_sizes, int n_in,
                              void* d_out, int out_size, void* d_ws, size_t ws_size,
                              hipStream_t stream) {
    const float* feat = (const float*)d_in[0];  // [100000, 128]
    const float* W1   = (const float*)d_in[1];  // [128, 128]
    const float* b1   = (const float*)d_in[2];  // [128]
    const float* W2   = (const float*)d_in[3];  // [128, 64]
    const float* b2   = (const float*)d_in[4];  // [64]
    const int*   src  = (const int*)d_in[5];    // [1600000]
    const int*   dst  = (const int*)d_in[6];    // [1600000]
    float* out = (float*)d_out;                 // [100000, 64]

    // Workspace layout:
    //   counts  : i32 [100000]   @ 0x0000000  (400,000 B)
    //   cursor  : i32 [100000]   @ 0x0080000  (400,000 B)
    //   bsums   : i32 [128]      @ 0x0100000
    //   offs    : i32 [100001]   @ 0x0180000  (400,004 B)
    //   csr_src : i32 [1600000]  @ 0x0200000  (6,400,000 B)
    //   neigh   : f32 [12.8M]    @ 0x0880000  (51,200,000 B)
    //   h1      : f32 [12.8M]    @ 0x3A00000  (51,200,000 B)
    // end ~= 112 MB
    char* ws = (char*)d_ws;
    int*   counts  = (int*)(ws + 0x0000000);
    int*   cursor  = (int*)(ws + 0x0080000);
    int*   bsums   = (int*)(ws + 0x0100000);
    int*   offs    = (int*)(ws + 0x0180000);
    int*   csr_src = (int*)(ws + 0x0200000);
    float* neigh   = (float*)(ws + 0x0880000);
    float* h1      = (float*)(ws + 0x3A00000);

    // ---- CSR build ----
    hipMemsetAsync(counts, 0, (size_t)NNODES * sizeof(int), stream);
    hipMemsetAsync(cursor, 0, (size_t)NNODES * sizeof(int), stream);

    hist_kernel<<<(NEDGES + 255) / 256, 256, 0, stream>>>(dst, counts);

    const int SCAN_BLOCKS = (NNODES + 1023) / 1024;  // 98
    scan_block<<<SCAN_BLOCKS, 256, 0, stream>>>(counts, offs, bsums);
    scan_sums<<<1, 1, 0, stream>>>(bsums, offs, SCAN_BLOCKS);
    scan_add<<<SCAN_BLOCKS, 256, 0, stream>>>(offs, bsums);

    fill_kernel<<<(NEDGES + 255) / 256, 256, 0, stream>>>(src, dst, offs, cursor,
                                                          csr_src);

    // ---- Layer 1: gather+normalize, then GEMM+relu ----
    {
        int blocks = (NNODES * 64 + 255) / 256;  // one wave per node
        gather_kernel<<<blocks, 256, 0, stream>>>((const float2*)feat, offs,
                                                  csr_src, (float2*)neigh);
    }
    {
        const int NPB = 8;
        int blocks = (NNODES + NPB - 1) / NPB;
        sage_gemm<HIDDEN, NPB, true><<<blocks, HIDDEN, 0, stream>>>(
            neigh, W1, b1, h1);
    }

    // ---- Layer 2: gather+normalize, then GEMM ----
    {
        int blocks = (NNODES * 64 + 255) / 256;
        gather_kernel<<<blocks, 256, 0, stream>>>((const float2*)h1, offs,
                                                  csr_src, (float2*)neigh);
    }
    {
        const int NPB = 16;
        int blocks = (NNODES + NPB - 1) / NPB;
        sage_gemm<OUTSIZE, NPB, false><<<blocks, OUTSIZE, 0, stream>>>(
            neigh, W2, b2, out);
    }
}

// Round 3
// 485.875 us; speedup vs baseline: 11.7580x; 1.5475x over previous
//
#include <hip/hip_runtime.h>

#define NNODES 100000
#define NEDGES 1600000

typedef _Float16 f16;
typedef _Float16 v2h __attribute__((ext_vector_type(2)));
typedef _Float16 v4h __attribute__((ext_vector_type(4)));
typedef _Float16 v8h __attribute__((ext_vector_type(8)));
typedef float v4f __attribute__((ext_vector_type(4)));

// ---------------------------------------------------------------------------
// fp32 -> f16 conversion (feat), 4 elements/thread.
// ---------------------------------------------------------------------------
__global__ void cvt_feat(const float4* __restrict__ in, v4h* __restrict__ out, int n4) {
    int i = blockIdx.x * blockDim.x + threadIdx.x;
    if (i >= n4) return;
    float4 v = in[i];
    v4h o = {(f16)v.x, (f16)v.y, (f16)v.z, (f16)v.w};
    out[i] = o;
}

// Transpose + convert W [K,N] fp32 -> Wt [N,K] f16. Tiny.
__global__ void cvt_w_t(const float* __restrict__ W, f16* __restrict__ Wt, int N) {
    int t = blockIdx.x * blockDim.x + threadIdx.x;
    if (t >= 128 * N) return;
    int k = t / N, n = t - k * N;
    Wt[n * 128 + k] = (f16)W[k * N + n];
}

// ---------------------------------------------------------------------------
// CSR build: histogram -> exclusive scan -> fill.
// ---------------------------------------------------------------------------
__global__ void hist_kernel(const int* __restrict__ dst, int* __restrict__ counts) {
    int e = blockIdx.x * blockDim.x + threadIdx.x;
    if (e < NEDGES) atomicAdd(&counts[dst[e]], 1);
}

__global__ void scan_block(const int* __restrict__ counts, int* __restrict__ offs,
                           int* __restrict__ bsums) {
    __shared__ int s[256];
    int tid = threadIdx.x;
    int base = blockIdx.x * 1024 + tid * 4;
    int v0 = (base + 0 < NNODES) ? counts[base + 0] : 0;
    int v1 = (base + 1 < NNODES) ? counts[base + 1] : 0;
    int v2 = (base + 2 < NNODES) ? counts[base + 2] : 0;
    int v3 = (base + 3 < NNODES) ? counts[base + 3] : 0;
    int tsum = v0 + v1 + v2 + v3;
    s[tid] = tsum;
    __syncthreads();
    for (int off = 1; off < 256; off <<= 1) {
        int t = (tid >= off) ? s[tid - off] : 0;
        __syncthreads();
        s[tid] += t;
        __syncthreads();
    }
    int excl = s[tid] - tsum;
    if (base + 0 < NNODES) offs[base + 0] = excl;
    if (base + 1 < NNODES) offs[base + 1] = excl + v0;
    if (base + 2 < NNODES) offs[base + 2] = excl + v0 + v1;
    if (base + 3 < NNODES) offs[base + 3] = excl + v0 + v1 + v2;
    if (tid == 255) bsums[blockIdx.x] = s[255];
}

__global__ void scan_sums(int* __restrict__ bsums, int* __restrict__ offs, int nblocks) {
    int run = 0;
    for (int i = 0; i < nblocks; i++) {
        int t = bsums[i];
        bsums[i] = run;
        run += t;
    }
    offs[NNODES] = run;
}

__global__ void scan_add(int* __restrict__ offs, const int* __restrict__ bsums) {
    int base = blockIdx.x * 1024 + threadIdx.x * 4;
    int add = bsums[blockIdx.x];
    if (base + 0 < NNODES) offs[base + 0] += add;
    if (base + 1 < NNODES) offs[base + 1] += add;
    if (base + 2 < NNODES) offs[base + 2] += add;
    if (base + 3 < NNODES) offs[base + 3] += add;
}

__global__ void fill_kernel(const int* __restrict__ src, const int* __restrict__ dst,
                            const int* __restrict__ offs, int* __restrict__ cursor,
                            int* __restrict__ csr_src) {
    int e = blockIdx.x * blockDim.x + threadIdx.x;
    if (e >= NEDGES) return;
    int d = dst[e];
    int slot = atomicAdd(&cursor[d], 1);
    csr_src[offs[d] + slot] = src[e];
}

// ---------------------------------------------------------------------------
// f16 gather + normalize: one wave per node, lane owns one half2 (4 B) of the
// 128-wide row (256 B/row, fully coalesced). fp32 accumulation.
//   out[n] = (sum_{e in in(n)} x[src[e]] + x[n]) / (deg(n) + 1)
// ---------------------------------------------------------------------------
__global__ void gather_h(const v2h* __restrict__ x,       // [NNODES*64]
                         const int* __restrict__ offs,
                         const int* __restrict__ csr,
                         v2h* __restrict__ out)            // [NNODES*64]
{
    int wid = (int)(((long)blockIdx.x * blockDim.x + threadIdx.x) >> 6);
    int lane = threadIdx.x & 63;
    if (wid >= NNODES) return;
    int beg = offs[wid];
    int end = offs[wid + 1];
    v2h sv = x[(long)wid * 64 + lane];
    float ax = (float)sv[0], ay = (float)sv[1];
    int e = beg;
    for (; e + 1 < end; e += 2) {
        int s0 = csr[e];
        int s1 = csr[e + 1];
        v2h u0 = x[(long)s0 * 64 + lane];
        v2h u1 = x[(long)s1 * 64 + lane];
        ax += (float)u0[0] + (float)u1[0];
        ay += (float)u0[1] + (float)u1[1];
    }
    if (e < end) {
        v2h u = x[(long)csr[e] * 64 + lane];
        ax += (float)u[0];
        ay += (float)u[1];
    }
    float inv = 1.0f / (float)(end - beg + 1);
    v2h o = {(f16)(ax * inv), (f16)(ay * inv)};
    out[(long)wid * 64 + lane] = o;
}

// ---------------------------------------------------------------------------
// MFMA f16 GEMM: out[m][n] = act(A[m] . Wt[n] + b[n]).
// A: [M,128] f16 row-major.  Wt: [NOUT,128] f16 (pre-transposed).
// Block = 256 threads = 4 waves; each wave computes a 16-row strip over all
// NOUT columns with mfma_f32_16x16x32_f16 (A frag: m=lane&15, k=quad*8+j;
// C/D: n=lane&15, m=quad*4+reg). Wt staged in LDS, pitch 136 halves (272 B)
// -> even 8-lane-per-bank-group distribution for ds_read_b128.
// ---------------------------------------------------------------------------
template <int NOUT, bool RELU, typename OutT>
__global__ __launch_bounds__(256) void gemm_mfma(
    const f16* __restrict__ A,     // [M,128]
    const f16* __restrict__ Wt,    // [NOUT,128]
    const float* __restrict__ bias, // [NOUT]
    OutT* __restrict__ out)        // [M,NOUT]
{
    constexpr int PITCH = 136;  // halves
    __shared__ f16 wlds[NOUT * PITCH];
    int tid = threadIdx.x;

    // Stage Wt into LDS (8-half chunks).
    for (int c = tid; c < NOUT * 16; c += 256) {
        int n = c >> 4;
        int kc = c & 15;
        *(v8h*)&wlds[n * PITCH + kc * 8] = *(const v8h*)&Wt[n * 128 + kc * 8];
    }
    __syncthreads();

    int wave = tid >> 6;
    int lane = tid & 63;
    int quad = lane >> 4;
    int l16 = lane & 15;
    int m0 = blockIdx.x * 64 + wave * 16;
    if (m0 >= NNODES) return;  // NNODES % 16 == 0, so strips are full or absent

    // A fragments for K=128 (4 k-blocks of 32).
    v8h a[4];
    const f16* arow = A + (long)(m0 + l16) * 128 + quad * 8;
#pragma unroll
    for (int kb = 0; kb < 4; kb++) a[kb] = *(const v8h*)(arow + kb * 32);

#pragma unroll
    for (int nt = 0; nt < NOUT / 16; nt++) {
        v4f acc = {0.f, 0.f, 0.f, 0.f};
        const f16* brow = &wlds[(nt * 16 + l16) * PITCH + quad * 8];
#pragma unroll
        for (int kb = 0; kb < 4; kb++) {
            v8h b = *(const v8h*)(brow + kb * 32);
            acc = __builtin_amdgcn_mfma_f32_16x16x32_f16(a[kb], b, acc, 0, 0, 0);
        }
        int n = nt * 16 + l16;
        float bj = bias[n];
#pragma unroll
        for (int r = 0; r < 4; r++) {
            int m = m0 + quad * 4 + r;
            float v = acc[r] + bj;
            if (RELU) v = fmaxf(v, 0.0f);
            out[(long)m * NOUT + n] = (OutT)v;
        }
    }
}

extern "C" void kernel_launch(void* const* d_in, const int* in_sizes, int n_in,
                              void* d_out, int out_size, void* d_ws, size_t ws_size,
                              hipStream_t stream) {
    const float* feat = (const float*)d_in[0];  // [100000, 128]
    const float* W1   = (const float*)d_in[1];  // [128, 128]
    const float* b1   = (const float*)d_in[2];  // [128]
    const float* W2   = (const float*)d_in[3];  // [128, 64]
    const float* b2   = (const float*)d_in[4];  // [64]
    const int*   src  = (const int*)d_in[5];    // [1600000]
    const int*   dst  = (const int*)d_in[6];    // [1600000]
    float* out = (float*)d_out;                 // [100000, 64]

    // Workspace layout:
    //   counts  i32[100000] @ 0x0000000
    //   cursor  i32[100000] @ 0x0080000
    //   bsums   i32[128]    @ 0x0100000
    //   offs    i32[100001] @ 0x0110000
    //   csr_src i32[1.6M]   @ 0x0180000  (6.4 MB)
    //   featH   f16[12.8M]  @ 0x0800000  (25.6 MB)
    //   neighH  f16[12.8M]  @ 0x2100000  (25.6 MB)
    //   h1H     f16[12.8M]  @ 0x3A00000  (25.6 MB)
    //   W1t     f16[16384]  @ 0x5300000  (32 KB)
    //   W2t     f16[8192]   @ 0x5310000  (16 KB)
    // end ~ 87.2 MB
    char* ws = (char*)d_ws;
    int* counts  = (int*)(ws + 0x0000000);
    int* cursor  = (int*)(ws + 0x0080000);
    int* bsums   = (int*)(ws + 0x0100000);
    int* offs    = (int*)(ws + 0x0110000);
    int* csr     = (int*)(ws + 0x0180000);
    f16* featH   = (f16*)(ws + 0x0800000);
    f16* neighH  = (f16*)(ws + 0x2100000);
    f16* h1H     = (f16*)(ws + 0x3A00000);
    f16* W1t     = (f16*)(ws + 0x5300000);
    f16* W2t     = (f16*)(ws + 0x5310000);

    // ---- conversions (independent of CSR build) ----
    {
        int n4 = NNODES * 128 / 4;  // 3.2M
        cvt_feat<<<(n4 + 255) / 256, 256, 0, stream>>>((const float4*)feat,
                                                       (v4h*)featH, n4);
    }
    cvt_w_t<<<(128 * 128 + 255) / 256, 256, 0, stream>>>(W1, W1t, 128);
    cvt_w_t<<<(128 * 64 + 255) / 256, 256, 0, stream>>>(W2, W2t, 64);

    // ---- CSR build ----
    hipMemsetAsync(counts, 0, (size_t)NNODES * sizeof(int), stream);
    hipMemsetAsync(cursor, 0, (size_t)NNODES * sizeof(int), stream);
    hist_kernel<<<(NEDGES + 255) / 256, 256, 0, stream>>>(dst, counts);
    const int SCAN_BLOCKS = (NNODES + 1023) / 1024;  // 98
    scan_block<<<SCAN_BLOCKS, 256, 0, stream>>>(counts, offs, bsums);
    scan_sums<<<1, 1, 0, stream>>>(bsums, offs, SCAN_BLOCKS);
    scan_add<<<SCAN_BLOCKS, 256, 0, stream>>>(offs, bsums);
    fill_kernel<<<(NEDGES + 255) / 256, 256, 0, stream>>>(src, dst, offs, cursor, csr);

    // ---- Layer 1 ----
    {
        int blocks = (NNODES * 64 + 255) / 256;  // one wave per node
        gather_h<<<blocks, 256, 0, stream>>>((const v2h*)featH, offs, csr,
                                             (v2h*)neighH);
    }
    {
        int blocks = (NNODES + 63) / 64;  // 1563
        gemm_mfma<128, true, f16><<<blocks, 256, 0, stream>>>(neighH, W1t, b1, h1H);
    }

    // ---- Layer 2 ----
    {
        int blocks = (NNODES * 64 + 255) / 256;
        gather_h<<<blocks, 256, 0, stream>>>((const v2h*)h1H, offs, csr,
                                             (v2h*)neighH);
    }
    {
        int blocks = (NNODES + 63) / 64;
        gemm_mfma<64, false, float><<<blocks, 256, 0, stream>>>(neighH, W2t, b2, out);
    }
}

// Round 4
// 471.731 us; speedup vs baseline: 12.1106x; 1.0300x over previous
//
#include <hip/hip_runtime.h>

#define NNODES 100000
#define NEDGES 1600000

typedef _Float16 f16;
typedef _Float16 v4h __attribute__((ext_vector_type(4)));
typedef _Float16 v8h __attribute__((ext_vector_type(8)));
typedef float v4f __attribute__((ext_vector_type(4)));

// ---------------------------------------------------------------------------
// fp32 -> f16 conversion (feat), 4 elements/thread.
// ---------------------------------------------------------------------------
__global__ void cvt_feat(const float4* __restrict__ in, v4h* __restrict__ out, int n4) {
    int i = blockIdx.x * blockDim.x + threadIdx.x;
    if (i >= n4) return;
    float4 v = in[i];
    v4h o = {(f16)v.x, (f16)v.y, (f16)v.z, (f16)v.w};
    out[i] = o;
}

// Transpose + convert W [K,N] fp32 -> Wt [N,K] f16. Tiny.
__global__ void cvt_w_t(const float* __restrict__ W, f16* __restrict__ Wt, int N) {
    int t = blockIdx.x * blockDim.x + threadIdx.x;
    if (t >= 128 * N) return;
    int k = t / N, n = t - k * N;
    Wt[n * 128 + k] = (f16)W[k * N + n];
}

// ---------------------------------------------------------------------------
// CSR build: histogram -> exclusive scan -> fill.
// ---------------------------------------------------------------------------
__global__ void hist_kernel(const int* __restrict__ dst, int* __restrict__ counts) {
    int e = blockIdx.x * blockDim.x + threadIdx.x;
    if (e < NEDGES) atomicAdd(&counts[dst[e]], 1);
}

__global__ void scan_block(const int* __restrict__ counts, int* __restrict__ offs,
                           int* __restrict__ bsums) {
    __shared__ int s[256];
    int tid = threadIdx.x;
    int base = blockIdx.x * 1024 + tid * 4;
    int v0 = (base + 0 < NNODES) ? counts[base + 0] : 0;
    int v1 = (base + 1 < NNODES) ? counts[base + 1] : 0;
    int v2 = (base + 2 < NNODES) ? counts[base + 2] : 0;
    int v3 = (base + 3 < NNODES) ? counts[base + 3] : 0;
    int tsum = v0 + v1 + v2 + v3;
    s[tid] = tsum;
    __syncthreads();
    for (int off = 1; off < 256; off <<= 1) {
        int t = (tid >= off) ? s[tid - off] : 0;
        __syncthreads();
        s[tid] += t;
        __syncthreads();
    }
    int excl = s[tid] - tsum;
    if (base + 0 < NNODES) offs[base + 0] = excl;
    if (base + 1 < NNODES) offs[base + 1] = excl + v0;
    if (base + 2 < NNODES) offs[base + 2] = excl + v0 + v1;
    if (base + 3 < NNODES) offs[base + 3] = excl + v0 + v1 + v2;
    if (tid == 255) bsums[blockIdx.x] = s[255];
}

__global__ void scan_sums(int* __restrict__ bsums, int* __restrict__ offs, int nblocks) {
    int run = 0;
    for (int i = 0; i < nblocks; i++) {
        int t = bsums[i];
        bsums[i] = run;
        run += t;
    }
    offs[NNODES] = run;
}

__global__ void scan_add(int* __restrict__ offs, const int* __restrict__ bsums) {
    int base = blockIdx.x * 1024 + threadIdx.x * 4;
    int add = bsums[blockIdx.x];
    if (base + 0 < NNODES) offs[base + 0] += add;
    if (base + 1 < NNODES) offs[base + 1] += add;
    if (base + 2 < NNODES) offs[base + 2] += add;
    if (base + 3 < NNODES) offs[base + 3] += add;
}

__global__ void fill_kernel(const int* __restrict__ src, const int* __restrict__ dst,
                            const int* __restrict__ offs, int* __restrict__ cursor,
                            int* __restrict__ csr_src) {
    int e = blockIdx.x * blockDim.x + threadIdx.x;
    if (e >= NEDGES) return;
    int d = dst[e];
    int slot = atomicAdd(&cursor[d], 1);
    csr_src[offs[d] + slot] = src[e];
}

// ---------------------------------------------------------------------------
// MFMA f16 GEMM: Z[m][n] = A[m] . Wt[n]  (no bias/act -- folded into gather).
// Block = 256 threads = 4 waves; each wave computes a 16-row strip.
// ---------------------------------------------------------------------------
template <int NOUT>
__global__ __launch_bounds__(256) void gemm_mfma(
    const f16* __restrict__ A,   // [M,128]
    const f16* __restrict__ Wt,  // [NOUT,128]
    f16* __restrict__ out)       // [M,NOUT]
{
    constexpr int PITCH = 136;  // halves
    __shared__ f16 wlds[NOUT * PITCH];
    int tid = threadIdx.x;

    for (int c = tid; c < NOUT * 16; c += 256) {
        int n = c >> 4;
        int kc = c & 15;
        *(v8h*)&wlds[n * PITCH + kc * 8] = *(const v8h*)&Wt[n * 128 + kc * 8];
    }
    __syncthreads();

    int wave = tid >> 6;
    int lane = tid & 63;
    int quad = lane >> 4;
    int l16 = lane & 15;
    int m0 = blockIdx.x * 64 + wave * 16;
    if (m0 >= NNODES) return;  // NNODES % 16 == 0

    v8h a[4];
    const f16* arow = A + (long)(m0 + l16) * 128 + quad * 8;
#pragma unroll
    for (int kb = 0; kb < 4; kb++) a[kb] = *(const v8h*)(arow + kb * 32);

#pragma unroll
    for (int nt = 0; nt < NOUT / 16; nt++) {
        v4f acc = {0.f, 0.f, 0.f, 0.f};
        const f16* brow = &wlds[(nt * 16 + l16) * PITCH + quad * 8];
#pragma unroll
        for (int kb = 0; kb < 4; kb++) {
            v8h b = *(const v8h*)(brow + kb * 32);
            acc = __builtin_amdgcn_mfma_f32_16x16x32_f16(a[kb], b, acc, 0, 0, 0);
        }
        int n = nt * 16 + l16;
#pragma unroll
        for (int r = 0; r < 4; r++) {
            int m = m0 + quad * 4 + r;
            out[(long)m * NOUT + n] = (f16)acc[r];
        }
    }
}

// ---------------------------------------------------------------------------
// Gather+normalize over 128-wide f16 rows (layer 1, post-projection):
//   h1[n] = relu( (Σ_{e in(n)} z[src[e]] + z[n]) / (deg+1) + b )
// One wave per node. Half-waves (32 lanes, v4h = 8B/lane) each own one edge;
// main loop does 4 edges/iter (2 row-loads in flight/lane). shfl_xor(32)
// combines the halves.
// ---------------------------------------------------------------------------
__global__ void gather128(const v4h* __restrict__ z,    // rows of 32 v4h
                          const int* __restrict__ offs,
                          const int* __restrict__ csr,
                          const float* __restrict__ bias,  // [128]
                          v4h* __restrict__ out)           // rows of 32 v4h
{
    int node = (int)(((long)blockIdx.x * blockDim.x + threadIdx.x) >> 6);
    if (node >= NNODES) return;
    int lane = threadIdx.x & 63;
    int half = lane >> 5;
    int c = lane & 31;

    int beg = offs[node];
    int end = offs[node + 1];
    float a0 = 0.f, a1 = 0.f, a2 = 0.f, a3 = 0.f;

    int e = beg;
    for (; e + 3 < end; e += 4) {
        int iA = csr[e + half];
        int iB = csr[e + 2 + half];
        v4h uA = z[(long)iA * 32 + c];
        v4h uB = z[(long)iB * 32 + c];
        a0 += (float)uA[0] + (float)uB[0];
        a1 += (float)uA[1] + (float)uB[1];
        a2 += (float)uA[2] + (float)uB[2];
        a3 += (float)uA[3] + (float)uB[3];
    }
    for (; e < end; e += 2) {
        int t = e + half;
        if (t < end) {
            v4h u = z[(long)csr[t] * 32 + c];
            a0 += (float)u[0];
            a1 += (float)u[1];
            a2 += (float)u[2];
            a3 += (float)u[3];
        }
    }
    if (half == 0) {  // self term, once
        v4h s = z[(long)node * 32 + c];
        a0 += (float)s[0];
        a1 += (float)s[1];
        a2 += (float)s[2];
        a3 += (float)s[3];
    }
    a0 += __shfl_xor(a0, 32);
    a1 += __shfl_xor(a1, 32);
    a2 += __shfl_xor(a2, 32);
    a3 += __shfl_xor(a3, 32);

    if (half == 0) {
        float inv = 1.0f / (float)(end - beg + 1);
        float4 b = ((const float4*)bias)[c];
        v4h o = {(f16)fmaxf(a0 * inv + b.x, 0.f),
                 (f16)fmaxf(a1 * inv + b.y, 0.f),
                 (f16)fmaxf(a2 * inv + b.z, 0.f),
                 (f16)fmaxf(a3 * inv + b.w, 0.f)};
        out[(long)node * 32 + c] = o;
    }
}

// ---------------------------------------------------------------------------
// Gather+normalize over 64-wide f16 rows (layer 2, post-projection), fp32 out:
//   out[n] = (Σ z2[src] + z2[n]) / (deg+1) + b2
// 16-lane subgroups own edges (4 edges in parallel), 8 edges/iter unrolled.
// ---------------------------------------------------------------------------
__global__ void gather64(const v4h* __restrict__ z,    // rows of 16 v4h
                         const int* __restrict__ offs,
                         const int* __restrict__ csr,
                         const float* __restrict__ bias,  // [64]
                         float4* __restrict__ out)        // rows of 16 float4
{
    int node = (int)(((long)blockIdx.x * blockDim.x + threadIdx.x) >> 6);
    if (node >= NNODES) return;
    int lane = threadIdx.x & 63;
    int sub = lane >> 4;
    int c = lane & 15;

    int beg = offs[node];
    int end = offs[node + 1];
    float a0 = 0.f, a1 = 0.f, a2 = 0.f, a3 = 0.f;

    int e = beg;
    for (; e + 7 < end; e += 8) {
        int iA = csr[e + sub];
        int iB = csr[e + 4 + sub];
        v4h uA = z[(long)iA * 16 + c];
        v4h uB = z[(long)iB * 16 + c];
        a0 += (float)uA[0] + (float)uB[0];
        a1 += (float)uA[1] + (float)uB[1];
        a2 += (float)uA[2] + (float)uB[2];
        a3 += (float)uA[3] + (float)uB[3];
    }
    for (; e < end; e += 4) {
        int t = e + sub;
        if (t < end) {
            v4h u = z[(long)csr[t] * 16 + c];
            a0 += (float)u[0];
            a1 += (float)u[1];
            a2 += (float)u[2];
            a3 += (float)u[3];
        }
    }
    if (sub == 0) {  // self term, once
        v4h s = z[(long)node * 16 + c];
        a0 += (float)s[0];
        a1 += (float)s[1];
        a2 += (float)s[2];
        a3 += (float)s[3];
    }
    a0 += __shfl_xor(a0, 16);  a0 += __shfl_xor(a0, 32);
    a1 += __shfl_xor(a1, 16);  a1 += __shfl_xor(a1, 32);
    a2 += __shfl_xor(a2, 16);  a2 += __shfl_xor(a2, 32);
    a3 += __shfl_xor(a3, 16);  a3 += __shfl_xor(a3, 32);

    if (sub == 0) {
        float inv = 1.0f / (float)(end - beg + 1);
        float4 b = ((const float4*)bias)[c];
        out[(long)node * 16 + c] =
            make_float4(a0 * inv + b.x, a1 * inv + b.y, a2 * inv + b.z, a3 * inv + b.w);
    }
}

extern "C" void kernel_launch(void* const* d_in, const int* in_sizes, int n_in,
                              void* d_out, int out_size, void* d_ws, size_t ws_size,
                              hipStream_t stream) {
    const float* feat = (const float*)d_in[0];  // [100000, 128]
    const float* W1   = (const float*)d_in[1];  // [128, 128]
    const float* b1   = (const float*)d_in[2];  // [128]
    const float* W2   = (const float*)d_in[3];  // [128, 64]
    const float* b2   = (const float*)d_in[4];  // [64]
    const int*   src  = (const int*)d_in[5];    // [1600000]
    const int*   dst  = (const int*)d_in[6];    // [1600000]
    float* out = (float*)d_out;                 // [100000, 64]

    // Workspace layout:
    //   counts i32[100000] @ 0x0000000
    //   cursor i32[100000] @ 0x0080000
    //   bsums  i32[128]    @ 0x0100000
    //   offs   i32[100001] @ 0x0110000
    //   csr    i32[1.6M]   @ 0x0180000  (6.4 MB)
    //   featH  f16[12.8M]  @ 0x0800000  (25.6 MB)
    //   z1     f16[12.8M]  @ 0x2100000  (25.6 MB)  (feat@W1)
    //   h1     f16[12.8M]  @ 0x3A00000  (25.6 MB)  (layer-1 output)
    //   z2     f16[6.4M]   @ 0x5300000  (12.8 MB)  (h1@W2)
    //   W1t    f16[16384]  @ 0x6000000
    //   W2t    f16[8192]   @ 0x6010000
    char* ws = (char*)d_ws;
    int* counts = (int*)(ws + 0x0000000);
    int* cursor = (int*)(ws + 0x0080000);
    int* bsums  = (int*)(ws + 0x0100000);
    int* offs   = (int*)(ws + 0x0110000);
    int* csr    = (int*)(ws + 0x0180000);
    f16* featH  = (f16*)(ws + 0x0800000);
    f16* z1     = (f16*)(ws + 0x2100000);
    f16* h1     = (f16*)(ws + 0x3A00000);
    f16* z2     = (f16*)(ws + 0x5300000);
    f16* W1t    = (f16*)(ws + 0x6000000);
    f16* W2t    = (f16*)(ws + 0x6010000);

    // ---- conversions ----
    {
        int n4 = NNODES * 128 / 4;
        cvt_feat<<<(n4 + 255) / 256, 256, 0, stream>>>((const float4*)feat,
                                                       (v4h*)featH, n4);
    }
    cvt_w_t<<<(128 * 128 + 255) / 256, 256, 0, stream>>>(W1, W1t, 128);
    cvt_w_t<<<(128 * 64 + 255) / 256, 256, 0, stream>>>(W2, W2t, 64);

    // ---- CSR build ----
    hipMemsetAsync(counts, 0, (size_t)NNODES * sizeof(int), stream);
    hipMemsetAsync(cursor, 0, (size_t)NNODES * sizeof(int), stream);
    hist_kernel<<<(NEDGES + 255) / 256, 256, 0, stream>>>(dst, counts);
    const int SCAN_BLOCKS = (NNODES + 1023) / 1024;  // 98
    scan_block<<<SCAN_BLOCKS, 256, 0, stream>>>(counts, offs, bsums);
    scan_sums<<<1, 1, 0, stream>>>(bsums, offs, SCAN_BLOCKS);
    scan_add<<<SCAN_BLOCKS, 256, 0, stream>>>(offs, bsums);
    fill_kernel<<<(NEDGES + 255) / 256, 256, 0, stream>>>(src, dst, offs, cursor, csr);

    const int GATHER_BLOCKS = (NNODES * 64 + 255) / 256;  // 25000
    const int GEMM_BLOCKS = (NNODES + 63) / 64;           // 1563

    // ---- Layer 1: project then gather ----
    gemm_mfma<128><<<GEMM_BLOCKS, 256, 0, stream>>>(featH, W1t, z1);
    gather128<<<GATHER_BLOCKS, 256, 0, stream>>>((const v4h*)z1, offs, csr, b1,
                                                 (v4h*)h1);

    // ---- Layer 2: project then gather ----
    gemm_mfma<64><<<GEMM_BLOCKS, 256, 0, stream>>>(h1, W2t, z2);
    gather64<<<GATHER_BLOCKS, 256, 0, stream>>>((const v4h*)z2, offs, csr, b2,
                                                (float4*)out);
}

// Round 5
// 385.409 us; speedup vs baseline: 14.8230x; 1.2240x over previous
//
#include <hip/hip_runtime.h>

#define NNODES 100000
#define NEDGES 1600000
#define NB 391      // coarse buckets of 256 nodes: bucket = dst >> 8
#define BSHIFT 8

typedef _Float16 f16;
typedef _Float16 v4h __attribute__((ext_vector_type(4)));
typedef _Float16 v8h __attribute__((ext_vector_type(8)));
typedef float v4f __attribute__((ext_vector_type(4)));

// Transpose + convert W [K,N] fp32 -> Wt [N,K] f16. Tiny.
__global__ void cvt_w_t(const float* __restrict__ W, f16* __restrict__ Wt, int N) {
    int t = blockIdx.x * blockDim.x + threadIdx.x;
    if (t >= 128 * N) return;
    int k = t / N, n = t - k * N;
    Wt[n * 128 + k] = (f16)W[k * N + n];
}

// ---------------------------------------------------------------------------
// CSR build, bucketed to localize scattered writes.
// Phase A: coarse bucket histogram (LDS hist -> one global atomic per bucket
// per block).
// ---------------------------------------------------------------------------
__global__ __launch_bounds__(256) void bucket_hist(const int* __restrict__ dst,
                                                   int* __restrict__ bhist) {
    __shared__ int h[NB];
    for (int i = threadIdx.x; i < NB; i += 256) h[i] = 0;
    __syncthreads();
    int base = blockIdx.x * 4096;
    for (int k = 0; k < 16; k++) {
        int e = base + k * 256 + threadIdx.x;
        if (e < NEDGES) atomicAdd(&h[dst[e] >> BSHIFT], 1);
    }
    __syncthreads();
    for (int i = threadIdx.x; i < NB; i += 256)
        if (h[i]) atomicAdd(&bhist[i], h[i]);
}

// Phase B: exclusive scan of the 391 bucket counts (one block), init cursors.
__global__ void bucket_scan(const int* __restrict__ bhist, int* __restrict__ boff,
                            int* __restrict__ bcur) {
    __shared__ int s[512];
    int tid = threadIdx.x;
    int v = (tid < NB) ? bhist[tid] : 0;
    s[tid] = v;
    __syncthreads();
    for (int off = 1; off < 512; off <<= 1) {
        int t = (tid >= off) ? s[tid - off] : 0;
        __syncthreads();
        s[tid] += t;
        __syncthreads();
    }
    int excl = s[tid] - v;
    if (tid < NB) { boff[tid] = excl; bcur[tid] = excl; }
    if (tid == NB - 1) boff[NB] = excl + v;
}

// Phase C: scatter edges into bucket-contiguous ebuf (block reserves a range
// per bucket, then LDS-cursor placement). Also builds the per-node histogram.
__global__ __launch_bounds__(256) void bucket_scatter(const int* __restrict__ src,
                                                      const int* __restrict__ dst,
                                                      int* __restrict__ counts,
                                                      int* __restrict__ bcur,
                                                      int2* __restrict__ ebuf) {
    __shared__ int h[NB];
    __shared__ int base_s[NB];
    for (int i = threadIdx.x; i < NB; i += 256) h[i] = 0;
    __syncthreads();
    int base = blockIdx.x * 4096;
    int d[16], sv[16];
    for (int k = 0; k < 16; k++) {
        int e = base + k * 256 + threadIdx.x;
        if (e < NEDGES) {
            d[k] = dst[e];
            sv[k] = src[e];
            atomicAdd(&h[d[k] >> BSHIFT], 1);
            atomicAdd(&counts[d[k]], 1);
        } else {
            d[k] = -1;
        }
    }
    __syncthreads();
    for (int i = threadIdx.x; i < NB; i += 256) {
        int c = h[i];
        if (c) base_s[i] = atomicAdd(&bcur[i], c);
        h[i] = 0;
    }
    __syncthreads();
    for (int k = 0; k < 16; k++) {
        if (d[k] >= 0) {
            int b = d[k] >> BSHIFT;
            int slot = atomicAdd(&h[b], 1);
            ebuf[base_s[b] + slot] = make_int2(sv[k], d[k]);
        }
    }
}

// Per-node exclusive scan: 1024 elems/block + block-sum scan + add-back.
__global__ void scan_block(const int* __restrict__ counts, int* __restrict__ offs,
                           int* __restrict__ bsums) {
    __shared__ int s[256];
    int tid = threadIdx.x;
    int base = blockIdx.x * 1024 + tid * 4;
    int v0 = (base + 0 < NNODES) ? counts[base + 0] : 0;
    int v1 = (base + 1 < NNODES) ? counts[base + 1] : 0;
    int v2 = (base + 2 < NNODES) ? counts[base + 2] : 0;
    int v3 = (base + 3 < NNODES) ? counts[base + 3] : 0;
    int tsum = v0 + v1 + v2 + v3;
    s[tid] = tsum;
    __syncthreads();
    for (int off = 1; off < 256; off <<= 1) {
        int t = (tid >= off) ? s[tid - off] : 0;
        __syncthreads();
        s[tid] += t;
        __syncthreads();
    }
    int excl = s[tid] - tsum;
    if (base + 0 < NNODES) offs[base + 0] = excl;
    if (base + 1 < NNODES) offs[base + 1] = excl + v0;
    if (base + 2 < NNODES) offs[base + 2] = excl + v0 + v1;
    if (base + 3 < NNODES) offs[base + 3] = excl + v0 + v1 + v2;
    if (tid == 255) bsums[blockIdx.x] = s[255];
}

__global__ void scan_sums2(int* __restrict__ bsums, int* __restrict__ offs,
                           int nblocks) {
    __shared__ int s[128];
    int tid = threadIdx.x;
    int v = (tid < nblocks) ? bsums[tid] : 0;
    s[tid] = v;
    __syncthreads();
    for (int off = 1; off < 128; off <<= 1) {
        int t = (tid >= off) ? s[tid - off] : 0;
        __syncthreads();
        s[tid] += t;
        __syncthreads();
    }
    if (tid < nblocks) bsums[tid] = s[tid] - v;
    if (tid == nblocks - 1) offs[NNODES] = s[tid];
}

__global__ void scan_add(int* __restrict__ offs, const int* __restrict__ bsums) {
    int base = blockIdx.x * 1024 + threadIdx.x * 4;
    int add = bsums[blockIdx.x];
    if (base + 0 < NNODES) offs[base + 0] += add;
    if (base + 1 < NNODES) offs[base + 1] += add;
    if (base + 2 < NNODES) offs[base + 2] += add;
    if (base + 3 < NNODES) offs[base + 3] += add;
}

// Phase D: per-bucket CSR fill. All writes land in this bucket's ~16KB CSR
// window; slots via LDS cursors.
__global__ __launch_bounds__(256) void fill_bucket(const int2* __restrict__ ebuf,
                                                   const int* __restrict__ boff,
                                                   const int* __restrict__ offs,
                                                   int* __restrict__ csr) {
    __shared__ int lcur[256];
    int b = blockIdx.x;
    lcur[threadIdx.x] = 0;
    __syncthreads();
    int ebeg = boff[b], eend = boff[b + 1];
    int nb = b << BSHIFT;
    for (int e = ebeg + threadIdx.x; e < eend; e += 256) {
        int2 ed = ebuf[e];
        int slot = atomicAdd(&lcur[ed.y - nb], 1);
        csr[offs[ed.y] + slot] = ed.x;
    }
}

// ---------------------------------------------------------------------------
// MFMA f16 GEMM (A already f16): Z[m][n] = A[m] . Wt[n].
// ---------------------------------------------------------------------------
template <int NOUT>
__global__ __launch_bounds__(256) void gemm_mfma(
    const f16* __restrict__ A,   // [M,128]
    const f16* __restrict__ Wt,  // [NOUT,128]
    f16* __restrict__ out)       // [M,NOUT]
{
    constexpr int PITCH = 136;
    __shared__ f16 wlds[NOUT * PITCH];
    int tid = threadIdx.x;
    for (int c = tid; c < NOUT * 16; c += 256) {
        int n = c >> 4;
        int kc = c & 15;
        *(v8h*)&wlds[n * PITCH + kc * 8] = *(const v8h*)&Wt[n * 128 + kc * 8];
    }
    __syncthreads();

    int wave = tid >> 6, lane = tid & 63, quad = lane >> 4, l16 = lane & 15;
    int m0 = blockIdx.x * 64 + wave * 16;
    if (m0 >= NNODES) return;

    v8h a[4];
    const f16* arow = A + (long)(m0 + l16) * 128 + quad * 8;
#pragma unroll
    for (int kb = 0; kb < 4; kb++) a[kb] = *(const v8h*)(arow + kb * 32);

#pragma unroll
    for (int nt = 0; nt < NOUT / 16; nt++) {
        v4f acc = {0.f, 0.f, 0.f, 0.f};
        const f16* brow = &wlds[(nt * 16 + l16) * PITCH + quad * 8];
#pragma unroll
        for (int kb = 0; kb < 4; kb++) {
            v8h b = *(const v8h*)(brow + kb * 32);
            acc = __builtin_amdgcn_mfma_f32_16x16x32_f16(a[kb], b, acc, 0, 0, 0);
        }
        int n = nt * 16 + l16;
#pragma unroll
        for (int r = 0; r < 4; r++)
            out[(long)(m0 + quad * 4 + r) * NOUT + n] = (f16)acc[r];
    }
}

// Same, but A is fp32 (fuses the feat fp32->f16 conversion into the load).
template <int NOUT>
__global__ __launch_bounds__(256) void gemm_mfma_f32in(
    const float* __restrict__ A,  // [M,128] fp32
    const f16* __restrict__ Wt,   // [NOUT,128]
    f16* __restrict__ out)        // [M,NOUT]
{
    constexpr int PITCH = 136;
    __shared__ f16 wlds[NOUT * PITCH];
    int tid = threadIdx.x;
    for (int c = tid; c < NOUT * 16; c += 256) {
        int n = c >> 4;
        int kc = c & 15;
        *(v8h*)&wlds[n * PITCH + kc * 8] = *(const v8h*)&Wt[n * 128 + kc * 8];
    }
    __syncthreads();

    int wave = tid >> 6, lane = tid & 63, quad = lane >> 4, l16 = lane & 15;
    int m0 = blockIdx.x * 64 + wave * 16;
    if (m0 >= NNODES) return;

    v8h a[4];
    const float* arow = A + (long)(m0 + l16) * 128 + quad * 8;
#pragma unroll
    for (int kb = 0; kb < 4; kb++) {
        float4 f0 = *(const float4*)(arow + kb * 32);
        float4 f1 = *(const float4*)(arow + kb * 32 + 4);
        v8h t = {(f16)f0.x, (f16)f0.y, (f16)f0.z, (f16)f0.w,
                 (f16)f1.x, (f16)f1.y, (f16)f1.z, (f16)f1.w};
        a[kb] = t;
    }

#pragma unroll
    for (int nt = 0; nt < NOUT / 16; nt++) {
        v4f acc = {0.f, 0.f, 0.f, 0.f};
        const f16* brow = &wlds[(nt * 16 + l16) * PITCH + quad * 8];
#pragma unroll
        for (int kb = 0; kb < 4; kb++) {
            v8h b = *(const v8h*)(brow + kb * 32);
            acc = __builtin_amdgcn_mfma_f32_16x16x32_f16(a[kb], b, acc, 0, 0, 0);
        }
        int n = nt * 16 + l16;
#pragma unroll
        for (int r = 0; r < 4; r++)
            out[(long)(m0 + quad * 4 + r) * NOUT + n] = (f16)acc[r];
    }
}

// ---------------------------------------------------------------------------
// Gather+normalize over 128-wide f16 rows (layer 1, post-projection):
//   h1[n] = relu( (Σ z[src] + z[n]) / (deg+1) + b1 )
// ---------------------------------------------------------------------------
__global__ void gather128(const v4h* __restrict__ z, const int* __restrict__ offs,
                          const int* __restrict__ csr, const float* __restrict__ bias,
                          v4h* __restrict__ out) {
    int node = (int)(((long)blockIdx.x * blockDim.x + threadIdx.x) >> 6);
    if (node >= NNODES) return;
    int lane = threadIdx.x & 63;
    int half = lane >> 5;
    int c = lane & 31;

    int beg = offs[node];
    int end = offs[node + 1];
    float a0 = 0.f, a1 = 0.f, a2 = 0.f, a3 = 0.f;

    int e = beg;
    for (; e + 3 < end; e += 4) {
        int iA = csr[e + half];
        int iB = csr[e + 2 + half];
        v4h uA = z[(long)iA * 32 + c];
        v4h uB = z[(long)iB * 32 + c];
        a0 += (float)uA[0] + (float)uB[0];
        a1 += (float)uA[1] + (float)uB[1];
        a2 += (float)uA[2] + (float)uB[2];
        a3 += (float)uA[3] + (float)uB[3];
    }
    for (; e < end; e += 2) {
        int t = e + half;
        if (t < end) {
            v4h u = z[(long)csr[t] * 32 + c];
            a0 += (float)u[0]; a1 += (float)u[1];
            a2 += (float)u[2]; a3 += (float)u[3];
        }
    }
    if (half == 0) {
        v4h s = z[(long)node * 32 + c];
        a0 += (float)s[0]; a1 += (float)s[1];
        a2 += (float)s[2]; a3 += (float)s[3];
    }
    a0 += __shfl_xor(a0, 32);
    a1 += __shfl_xor(a1, 32);
    a2 += __shfl_xor(a2, 32);
    a3 += __shfl_xor(a3, 32);

    if (half == 0) {
        float inv = 1.0f / (float)(end - beg + 1);
        float4 b = ((const float4*)bias)[c];
        v4h o = {(f16)fmaxf(a0 * inv + b.x, 0.f),
                 (f16)fmaxf(a1 * inv + b.y, 0.f),
                 (f16)fmaxf(a2 * inv + b.z, 0.f),
                 (f16)fmaxf(a3 * inv + b.w, 0.f)};
        out[(long)node * 32 + c] = o;
    }
}

// ---------------------------------------------------------------------------
// Gather+normalize over 64-wide f16 rows (layer 2), fp32 out:
//   out[n] = (Σ z2[src] + z2[n]) / (deg+1) + b2
// ---------------------------------------------------------------------------
__global__ void gather64(const v4h* __restrict__ z, const int* __restrict__ offs,
                         const int* __restrict__ csr, const float* __restrict__ bias,
                         float4* __restrict__ out) {
    int node = (int)(((long)blockIdx.x * blockDim.x + threadIdx.x) >> 6);
    if (node >= NNODES) return;
    int lane = threadIdx.x & 63;
    int sub = lane >> 4;
    int c = lane & 15;

    int beg = offs[node];
    int end = offs[node + 1];
    float a0 = 0.f, a1 = 0.f, a2 = 0.f, a3 = 0.f;

    int e = beg;
    for (; e + 7 < end; e += 8) {
        int iA = csr[e + sub];
        int iB = csr[e + 4 + sub];
        v4h uA = z[(long)iA * 16 + c];
        v4h uB = z[(long)iB * 16 + c];
        a0 += (float)uA[0] + (float)uB[0];
        a1 += (float)uA[1] + (float)uB[1];
        a2 += (float)uA[2] + (float)uB[2];
        a3 += (float)uA[3] + (float)uB[3];
    }
    for (; e < end; e += 4) {
        int t = e + sub;
        if (t < end) {
            v4h u = z[(long)csr[t] * 16 + c];
            a0 += (float)u[0]; a1 += (float)u[1];
            a2 += (float)u[2]; a3 += (float)u[3];
        }
    }
    if (sub == 0) {
        v4h s = z[(long)node * 16 + c];
        a0 += (float)s[0]; a1 += (float)s[1];
        a2 += (float)s[2]; a3 += (float)s[3];
    }
    a0 += __shfl_xor(a0, 16);  a0 += __shfl_xor(a0, 32);
    a1 += __shfl_xor(a1, 16);  a1 += __shfl_xor(a1, 32);
    a2 += __shfl_xor(a2, 16);  a2 += __shfl_xor(a2, 32);
    a3 += __shfl_xor(a3, 16);  a3 += __shfl_xor(a3, 32);

    if (sub == 0) {
        float inv = 1.0f / (float)(end - beg + 1);
        float4 b = ((const float4*)bias)[c];
        out[(long)node * 16 + c] =
            make_float4(a0 * inv + b.x, a1 * inv + b.y, a2 * inv + b.z, a3 * inv + b.w);
    }
}

extern "C" void kernel_launch(void* const* d_in, const int* in_sizes, int n_in,
                              void* d_out, int out_size, void* d_ws, size_t ws_size,
                              hipStream_t stream) {
    const float* feat = (const float*)d_in[0];
    const float* W1   = (const float*)d_in[1];
    const float* b1   = (const float*)d_in[2];
    const float* W2   = (const float*)d_in[3];
    const float* b2   = (const float*)d_in[4];
    const int*   src  = (const int*)d_in[5];
    const int*   dst  = (const int*)d_in[6];
    float* out = (float*)d_out;

    // Workspace layout:
    //   counts i32[100000] @ 0x0000000 (400000 B)   \ one memset
    //   bhist  i32[391]    @ 0x0061A80 (1564 B)     /
    //   boff   i32[392]    @ 0x0062800
    //   bcur   i32[391]    @ 0x0063800
    //   bsums  i32[128]    @ 0x0064800
    //   offs   i32[100001] @ 0x0065000
    //   csr    i32[1.6M]   @ 0x00C7000 (6.4 MB)
    //   ebuf   int2[1.6M]  @ 0x0700000 (12.8 MB)
    //   z1     f16[12.8M]  @ 0x1400000 (25.6 MB)
    //   h1     f16[12.8M]  @ 0x2E00000 (25.6 MB)
    //   z2     f16[6.4M]   @ 0x4800000 (12.8 MB)
    //   W1t    f16[16384]  @ 0x5500000
    //   W2t    f16[8192]   @ 0x5510000
    char* ws = (char*)d_ws;
    int*  counts = (int*)(ws + 0x0000000);
    int*  bhist  = (int*)(ws + 0x0061A80);
    int*  boff   = (int*)(ws + 0x0062800);
    int*  bcur   = (int*)(ws + 0x0063800);
    int*  bsums  = (int*)(ws + 0x0064800);
    int*  offs   = (int*)(ws + 0x0065000);
    int*  csr    = (int*)(ws + 0x00C7000);
    int2* ebuf   = (int2*)(ws + 0x0700000);
    f16*  z1     = (f16*)(ws + 0x1400000);
    f16*  h1     = (f16*)(ws + 0x2E00000);
    f16*  z2     = (f16*)(ws + 0x4800000);
    f16*  W1t    = (f16*)(ws + 0x5500000);
    f16*  W2t    = (f16*)(ws + 0x5510000);

    // ---- weight prep ----
    cvt_w_t<<<(128 * 128 + 255) / 256, 256, 0, stream>>>(W1, W1t, 128);
    cvt_w_t<<<(128 * 64 + 255) / 256, 256, 0, stream>>>(W2, W2t, 64);

    // ---- CSR build (bucketed) ----
    hipMemsetAsync(counts, 0, 400000 + 0x1000, stream);  // counts + bhist
    const int EBLOCKS = (NEDGES + 4095) / 4096;  // 391
    bucket_hist<<<EBLOCKS, 256, 0, stream>>>(dst, bhist);
    bucket_scan<<<1, 512, 0, stream>>>(bhist, boff, bcur);
    bucket_scatter<<<EBLOCKS, 256, 0, stream>>>(src, dst, counts, bcur, ebuf);
    const int SCAN_BLOCKS = (NNODES + 1023) / 1024;  // 98
    scan_block<<<SCAN_BLOCKS, 256, 0, stream>>>(counts, offs, bsums);
    scan_sums2<<<1, 128, 0, stream>>>(bsums, offs, SCAN_BLOCKS);
    scan_add<<<SCAN_BLOCKS, 256, 0, stream>>>(offs, bsums);
    fill_bucket<<<NB, 256, 0, stream>>>(ebuf, boff, offs, csr);

    const int GATHER_BLOCKS = (NNODES * 64 + 255) / 256;  // 25000
    const int GEMM_BLOCKS = (NNODES + 63) / 64;           // 1563

    // ---- Layer 1: project (fused fp32->f16) then gather ----
    gemm_mfma_f32in<128><<<GEMM_BLOCKS, 256, 0, stream>>>(feat, W1t, z1);
    gather128<<<GATHER_BLOCKS, 256, 0, stream>>>((const v4h*)z1, offs, csr, b1,
                                                 (v4h*)h1);

    // ---- Layer 2: project then gather ----
    gemm_mfma<64><<<GEMM_BLOCKS, 256, 0, stream>>>(h1, W2t, z2);
    gather64<<<GATHER_BLOCKS, 256, 0, stream>>>((const v4h*)z2, offs, csr, b2,
                                                (float4*)out);
}

// Round 6
// 292.349 us; speedup vs baseline: 19.5415x; 1.3183x over previous
//
#include <hip/hip_runtime.h>

#define NNODES 100000
#define NEDGES 1600000
#define NB 391      // coarse buckets of 256 nodes: bucket = dst >> 8
#define BSHIFT 8

typedef _Float16 f16;
typedef _Float16 v4h __attribute__((ext_vector_type(4)));
typedef _Float16 v8h __attribute__((ext_vector_type(8)));
typedef float v4f __attribute__((ext_vector_type(4)));

// Transpose + convert both weights fp32 [K,N] -> f16 [N,K]. Tiny, one launch.
__global__ void cvt_w_both(const float* __restrict__ W1, f16* __restrict__ W1t,
                           const float* __restrict__ W2, f16* __restrict__ W2t) {
    int t = blockIdx.x * blockDim.x + threadIdx.x;
    if (t < 128 * 128) {
        int k = t >> 7, n = t & 127;
        W1t[n * 128 + k] = (f16)W1[k * 128 + n];
    } else if (t < 128 * 128 + 128 * 64) {
        int u = t - 128 * 128;
        int k = u >> 6, n = u & 63;
        W2t[n * 128 + k] = (f16)W2[k * 64 + n];
    }
}

// ---------------------------------------------------------------------------
// CSR build, bucketed. Phase A: coarse bucket histogram.
// ---------------------------------------------------------------------------
__global__ __launch_bounds__(256) void bucket_hist(const int* __restrict__ dst,
                                                   int* __restrict__ bhist) {
    __shared__ int h[NB];
    for (int i = threadIdx.x; i < NB; i += 256) h[i] = 0;
    __syncthreads();
    int base = blockIdx.x * 4096;
    for (int k = 0; k < 16; k++) {
        int e = base + k * 256 + threadIdx.x;
        if (e < NEDGES) atomicAdd(&h[dst[e] >> BSHIFT], 1);
    }
    __syncthreads();
    for (int i = threadIdx.x; i < NB; i += 256)
        if (h[i]) atomicAdd(&bhist[i], h[i]);
}

// Phase B: exclusive scan of bucket counts (one block), init cursors.
__global__ void bucket_scan(const int* __restrict__ bhist, int* __restrict__ boff,
                            int* __restrict__ bcur) {
    __shared__ int s[512];
    int tid = threadIdx.x;
    int v = (tid < NB) ? bhist[tid] : 0;
    s[tid] = v;
    __syncthreads();
    for (int off = 1; off < 512; off <<= 1) {
        int t = (tid >= off) ? s[tid - off] : 0;
        __syncthreads();
        s[tid] += t;
        __syncthreads();
    }
    int excl = s[tid] - v;
    if (tid < NB) { boff[tid] = excl; bcur[tid] = excl; }
    if (tid == NB - 1) boff[NB] = excl + v;
}

// Phase C: scatter edges into bucket-contiguous ebuf, packed 4B each:
//   entry = src | ((dst & 255) << 24)   (src < 2^17)
__global__ __launch_bounds__(256) void bucket_scatter(const int* __restrict__ src,
                                                      const int* __restrict__ dst,
                                                      int* __restrict__ bcur,
                                                      int* __restrict__ ebuf) {
    __shared__ int h[NB];
    __shared__ int base_s[NB];
    for (int i = threadIdx.x; i < NB; i += 256) h[i] = 0;
    __syncthreads();
    int base = blockIdx.x * 4096;
    int d[16], sv[16];
    for (int k = 0; k < 16; k++) {
        int e = base + k * 256 + threadIdx.x;
        if (e < NEDGES) {
            d[k] = dst[e];
            sv[k] = src[e];
            atomicAdd(&h[d[k] >> BSHIFT], 1);
        } else {
            d[k] = -1;
        }
    }
    __syncthreads();
    for (int i = threadIdx.x; i < NB; i += 256) {
        int c = h[i];
        if (c) base_s[i] = atomicAdd(&bcur[i], c);
        h[i] = 0;
    }
    __syncthreads();
    for (int k = 0; k < 16; k++) {
        if (d[k] >= 0) {
            int b = d[k] >> BSHIFT;
            int slot = atomicAdd(&h[b], 1);
            ebuf[base_s[b] + slot] = sv[k] | ((d[k] & 255) << 24);
        }
    }
}

// Phase D: per-bucket CSR fill + offs computation. One block per bucket:
// count the bucket's 256 nodes in LDS, exclusive-scan in LDS, write offs,
// then place edges via LDS cursors. All CSR writes land in a ~16KB window.
__global__ __launch_bounds__(256) void fill_bucket(const int* __restrict__ ebuf,
                                                   const int* __restrict__ boff,
                                                   int* __restrict__ offs,
                                                   int* __restrict__ csr) {
    __shared__ int lc[256];    // per-node counts, then cursors
    __shared__ int ls[256];    // scan array
    int b = blockIdx.x;
    int tid = threadIdx.x;
    lc[tid] = 0;
    __syncthreads();
    int ebeg = boff[b], eend = boff[b + 1];
    // pass 1: count
    for (int e = ebeg + tid; e < eend; e += 256)
        atomicAdd(&lc[((unsigned)ebuf[e]) >> 24], 1);
    __syncthreads();
    int cnt = lc[tid];
    ls[tid] = cnt;
    __syncthreads();
    for (int off = 1; off < 256; off <<= 1) {
        int t = (tid >= off) ? ls[tid - off] : 0;
        __syncthreads();
        ls[tid] += t;
        __syncthreads();
    }
    int excl = ls[tid] - cnt;
    int nb = b << BSHIFT;
    int node = nb + tid;
    if (node < NNODES) offs[node] = ebeg + excl;
    if (node == NNODES - 1) offs[NNODES] = NEDGES;
    ls[tid] = excl;   // keep exclusive offsets
    lc[tid] = 0;      // reset as cursors
    __syncthreads();
    // pass 2: place
    for (int e = ebeg + tid; e < eend; e += 256) {
        int p = ebuf[e];
        int dloc = ((unsigned)p) >> 24;
        int slot = atomicAdd(&lc[dloc], 1);
        csr[ebeg + ls[dloc] + slot] = p & 0xFFFFFF;
    }
}

// ---------------------------------------------------------------------------
// MFMA f16 GEMM (A already f16): Z[m][n] = A[m] . Wt[n].
// ---------------------------------------------------------------------------
template <int NOUT>
__global__ __launch_bounds__(256) void gemm_mfma(
    const f16* __restrict__ A, const f16* __restrict__ Wt, f16* __restrict__ out) {
    constexpr int PITCH = 136;
    __shared__ f16 wlds[NOUT * PITCH];
    int tid = threadIdx.x;
    for (int c = tid; c < NOUT * 16; c += 256) {
        int n = c >> 4;
        int kc = c & 15;
        *(v8h*)&wlds[n * PITCH + kc * 8] = *(const v8h*)&Wt[n * 128 + kc * 8];
    }
    __syncthreads();

    int wave = tid >> 6, lane = tid & 63, quad = lane >> 4, l16 = lane & 15;
    int m0 = blockIdx.x * 64 + wave * 16;
    if (m0 >= NNODES) return;

    v8h a[4];
    const f16* arow = A + (long)(m0 + l16) * 128 + quad * 8;
#pragma unroll
    for (int kb = 0; kb < 4; kb++) a[kb] = *(const v8h*)(arow + kb * 32);

#pragma unroll
    for (int nt = 0; nt < NOUT / 16; nt++) {
        v4f acc = {0.f, 0.f, 0.f, 0.f};
        const f16* brow = &wlds[(nt * 16 + l16) * PITCH + quad * 8];
#pragma unroll
        for (int kb = 0; kb < 4; kb++) {
            v8h b = *(const v8h*)(brow + kb * 32);
            acc = __builtin_amdgcn_mfma_f32_16x16x32_f16(a[kb], b, acc, 0, 0, 0);
        }
        int n = nt * 16 + l16;
#pragma unroll
        for (int r = 0; r < 4; r++)
            out[(long)(m0 + quad * 4 + r) * NOUT + n] = (f16)acc[r];
    }
}

// Same, but A is fp32 (fuses feat conversion into the load).
template <int NOUT>
__global__ __launch_bounds__(256) void gemm_mfma_f32in(
    const float* __restrict__ A, const f16* __restrict__ Wt, f16* __restrict__ out) {
    constexpr int PITCH = 136;
    __shared__ f16 wlds[NOUT * PITCH];
    int tid = threadIdx.x;
    for (int c = tid; c < NOUT * 16; c += 256) {
        int n = c >> 4;
        int kc = c & 15;
        *(v8h*)&wlds[n * PITCH + kc * 8] = *(const v8h*)&Wt[n * 128 + kc * 8];
    }
    __syncthreads();

    int wave = tid >> 6, lane = tid & 63, quad = lane >> 4, l16 = lane & 15;
    int m0 = blockIdx.x * 64 + wave * 16;
    if (m0 >= NNODES) return;

    v8h a[4];
    const float* arow = A + (long)(m0 + l16) * 128 + quad * 8;
#pragma unroll
    for (int kb = 0; kb < 4; kb++) {
        float4 f0 = *(const float4*)(arow + kb * 32);
        float4 f1 = *(const float4*)(arow + kb * 32 + 4);
        v8h t = {(f16)f0.x, (f16)f0.y, (f16)f0.z, (f16)f0.w,
                 (f16)f1.x, (f16)f1.y, (f16)f1.z, (f16)f1.w};
        a[kb] = t;
    }

#pragma unroll
    for (int nt = 0; nt < NOUT / 16; nt++) {
        v4f acc = {0.f, 0.f, 0.f, 0.f};
        const f16* brow = &wlds[(nt * 16 + l16) * PITCH + quad * 8];
#pragma unroll
        for (int kb = 0; kb < 4; kb++) {
            v8h b = *(const v8h*)(brow + kb * 32);
            acc = __builtin_amdgcn_mfma_f32_16x16x32_f16(a[kb], b, acc, 0, 0, 0);
        }
        int n = nt * 16 + l16;
#pragma unroll
        for (int r = 0; r < 4; r++)
            out[(long)(m0 + quad * 4 + r) * NOUT + n] = (f16)acc[r];
    }
}

// ---------------------------------------------------------------------------
// Gather+normalize, 128-wide f16 rows (layer 1):
//   h1[n] = relu( (Σ z[src] + z[n]) / (deg+1) + b1 )
// One wave/node; half-waves own edges; main loop 8 edges/iter = 4 row-loads
// in flight per lane (MLP).
// ---------------------------------------------------------------------------
__global__ void gather128(const v4h* __restrict__ z, const int* __restrict__ offs,
                          const int* __restrict__ csr, const float* __restrict__ bias,
                          v4h* __restrict__ out) {
    int node = (int)(((long)blockIdx.x * blockDim.x + threadIdx.x) >> 6);
    if (node >= NNODES) return;
    int lane = threadIdx.x & 63;
    int half = lane >> 5;
    int c = lane & 31;

    int beg = offs[node];
    int end = offs[node + 1];
    float a0 = 0.f, a1 = 0.f, a2 = 0.f, a3 = 0.f;

    int e = beg;
    for (; e + 7 < end; e += 8) {
        int i0 = csr[e + half];
        int i1 = csr[e + 2 + half];
        int i2 = csr[e + 4 + half];
        int i3 = csr[e + 6 + half];
        v4h u0 = z[(long)i0 * 32 + c];
        v4h u1 = z[(long)i1 * 32 + c];
        v4h u2 = z[(long)i2 * 32 + c];
        v4h u3 = z[(long)i3 * 32 + c];
        a0 += (float)u0[0] + (float)u1[0] + (float)u2[0] + (float)u3[0];
        a1 += (float)u0[1] + (float)u1[1] + (float)u2[1] + (float)u3[1];
        a2 += (float)u0[2] + (float)u1[2] + (float)u2[2] + (float)u3[2];
        a3 += (float)u0[3] + (float)u1[3] + (float)u2[3] + (float)u3[3];
    }
    for (; e + 3 < end; e += 4) {
        int i0 = csr[e + half];
        int i1 = csr[e + 2 + half];
        v4h u0 = z[(long)i0 * 32 + c];
        v4h u1 = z[(long)i1 * 32 + c];
        a0 += (float)u0[0] + (float)u1[0];
        a1 += (float)u0[1] + (float)u1[1];
        a2 += (float)u0[2] + (float)u1[2];
        a3 += (float)u0[3] + (float)u1[3];
    }
    for (; e < end; e += 2) {
        int t = e + half;
        if (t < end) {
            v4h u = z[(long)csr[t] * 32 + c];
            a0 += (float)u[0]; a1 += (float)u[1];
            a2 += (float)u[2]; a3 += (float)u[3];
        }
    }
    if (half == 0) {
        v4h s = z[(long)node * 32 + c];
        a0 += (float)s[0]; a1 += (float)s[1];
        a2 += (float)s[2]; a3 += (float)s[3];
    }
    a0 += __shfl_xor(a0, 32);
    a1 += __shfl_xor(a1, 32);
    a2 += __shfl_xor(a2, 32);
    a3 += __shfl_xor(a3, 32);

    if (half == 0) {
        float inv = 1.0f / (float)(end - beg + 1);
        float4 b = ((const float4*)bias)[c];
        v4h o = {(f16)fmaxf(a0 * inv + b.x, 0.f),
                 (f16)fmaxf(a1 * inv + b.y, 0.f),
                 (f16)fmaxf(a2 * inv + b.z, 0.f),
                 (f16)fmaxf(a3 * inv + b.w, 0.f)};
        out[(long)node * 32 + c] = o;
    }
}

// ---------------------------------------------------------------------------
// Gather+normalize, 64-wide f16 rows (layer 2), fp32 out:
//   out[n] = (Σ z2[src] + z2[n]) / (deg+1) + b2
// 16-lane subgroups own edges; main loop 16 edges/iter = 4 loads in flight.
// ---------------------------------------------------------------------------
__global__ void gather64(const v4h* __restrict__ z, const int* __restrict__ offs,
                         const int* __restrict__ csr, const float* __restrict__ bias,
                         float4* __restrict__ out) {
    int node = (int)(((long)blockIdx.x * blockDim.x + threadIdx.x) >> 6);
    if (node >= NNODES) return;
    int lane = threadIdx.x & 63;
    int sub = lane >> 4;
    int c = lane & 15;

    int beg = offs[node];
    int end = offs[node + 1];
    float a0 = 0.f, a1 = 0.f, a2 = 0.f, a3 = 0.f;

    int e = beg;
    for (; e + 15 < end; e += 16) {
        int i0 = csr[e + sub];
        int i1 = csr[e + 4 + sub];
        int i2 = csr[e + 8 + sub];
        int i3 = csr[e + 12 + sub];
        v4h u0 = z[(long)i0 * 16 + c];
        v4h u1 = z[(long)i1 * 16 + c];
        v4h u2 = z[(long)i2 * 16 + c];
        v4h u3 = z[(long)i3 * 16 + c];
        a0 += (float)u0[0] + (float)u1[0] + (float)u2[0] + (float)u3[0];
        a1 += (float)u0[1] + (float)u1[1] + (float)u2[1] + (float)u3[1];
        a2 += (float)u0[2] + (float)u1[2] + (float)u2[2] + (float)u3[2];
        a3 += (float)u0[3] + (float)u1[3] + (float)u2[3] + (float)u3[3];
    }
    for (; e + 7 < end; e += 8) {
        int i0 = csr[e + sub];
        int i1 = csr[e + 4 + sub];
        v4h u0 = z[(long)i0 * 16 + c];
        v4h u1 = z[(long)i1 * 16 + c];
        a0 += (float)u0[0] + (float)u1[0];
        a1 += (float)u0[1] + (float)u1[1];
        a2 += (float)u0[2] + (float)u1[2];
        a3 += (float)u0[3] + (float)u1[3];
    }
    for (; e < end; e += 4) {
        int t = e + sub;
        if (t < end) {
            v4h u = z[(long)csr[t] * 16 + c];
            a0 += (float)u[0]; a1 += (float)u[1];
            a2 += (float)u[2]; a3 += (float)u[3];
        }
    }
    if (sub == 0) {
        v4h s = z[(long)node * 16 + c];
        a0 += (float)s[0]; a1 += (float)s[1];
        a2 += (float)s[2]; a3 += (float)s[3];
    }
    a0 += __shfl_xor(a0, 16);  a0 += __shfl_xor(a0, 32);
    a1 += __shfl_xor(a1, 16);  a1 += __shfl_xor(a1, 32);
    a2 += __shfl_xor(a2, 16);  a2 += __shfl_xor(a2, 32);
    a3 += __shfl_xor(a3, 16);  a3 += __shfl_xor(a3, 32);

    if (sub == 0) {
        float inv = 1.0f / (float)(end - beg + 1);
        float4 b = ((const float4*)bias)[c];
        out[(long)node * 16 + c] =
            make_float4(a0 * inv + b.x, a1 * inv + b.y, a2 * inv + b.z, a3 * inv + b.w);
    }
}

extern "C" void kernel_launch(void* const* d_in, const int* in_sizes, int n_in,
                              void* d_out, int out_size, void* d_ws, size_t ws_size,
                              hipStream_t stream) {
    const float* feat = (const float*)d_in[0];
    const float* W1   = (const float*)d_in[1];
    const float* b1   = (const float*)d_in[2];
    const float* W2   = (const float*)d_in[3];
    const float* b2   = (const float*)d_in[4];
    const int*   src  = (const int*)d_in[5];
    const int*   dst  = (const int*)d_in[6];
    float* out = (float*)d_out;

    // Workspace layout:
    //   bhist i32[391]    @ 0x0000000
    //   boff  i32[392]    @ 0x0001000
    //   bcur  i32[391]    @ 0x0002000
    //   offs  i32[100001] @ 0x0003000  (400004 B)
    //   csr   i32[1.6M]   @ 0x0070000  (6.4 MB)
    //   ebuf  i32[1.6M]   @ 0x0700000  (6.4 MB, packed src|dloc<<24)
    //   z1    f16[12.8M]  @ 0x0E00000  (25.6 MB)
    //   h1    f16[12.8M]  @ 0x2700000  (25.6 MB)
    //   z2    f16[6.4M]   @ 0x4000000  (12.8 MB)
    //   W1t   f16[16384]  @ 0x4D00000
    //   W2t   f16[8192]   @ 0x4D10000
    char* ws = (char*)d_ws;
    int* bhist = (int*)(ws + 0x0000000);
    int* boff  = (int*)(ws + 0x0001000);
    int* bcur  = (int*)(ws + 0x0002000);
    int* offs  = (int*)(ws + 0x0003000);
    int* csr   = (int*)(ws + 0x0070000);
    int* ebuf  = (int*)(ws + 0x0700000);
    f16* z1    = (f16*)(ws + 0x0E00000);
    f16* h1    = (f16*)(ws + 0x2700000);
    f16* z2    = (f16*)(ws + 0x4000000);
    f16* W1t   = (f16*)(ws + 0x4D00000);
    f16* W2t   = (f16*)(ws + 0x4D10000);

    // ---- weight prep ----
    cvt_w_both<<<(128 * 128 + 128 * 64 + 255) / 256, 256, 0, stream>>>(W1, W1t, W2, W2t);

    // ---- CSR build (bucketed, no global per-node scan) ----
    hipMemsetAsync(bhist, 0, NB * sizeof(int), stream);
    const int EBLOCKS = (NEDGES + 4095) / 4096;  // 391
    bucket_hist<<<EBLOCKS, 256, 0, stream>>>(dst, bhist);
    bucket_scan<<<1, 512, 0, stream>>>(bhist, boff, bcur);
    bucket_scatter<<<EBLOCKS, 256, 0, stream>>>(src, dst, bcur, ebuf);
    fill_bucket<<<NB, 256, 0, stream>>>(ebuf, boff, offs, csr);

    const int GATHER_BLOCKS = (NNODES * 64 + 255) / 256;  // 25000
    const int GEMM_BLOCKS = (NNODES + 63) / 64;           // 1563

    // ---- Layer 1: project (fused fp32->f16) then gather ----
    gemm_mfma_f32in<128><<<GEMM_BLOCKS, 256, 0, stream>>>(feat, W1t, z1);
    gather128<<<GATHER_BLOCKS, 256, 0, stream>>>((const v4h*)z1, offs, csr, b1,
                                                 (v4h*)h1);

    // ---- Layer 2: project then gather ----
    gemm_mfma<64><<<GEMM_BLOCKS, 256, 0, stream>>>(h1, W2t, z2);
    gather64<<<GATHER_BLOCKS, 256, 0, stream>>>((const v4h*)z2, offs, csr, b2,
                                                (float4*)out);
}

// Round 7
// 278.329 us; speedup vs baseline: 20.5258x; 1.0504x over previous
//
#include <hip/hip_runtime.h>

#define NNODES 100000
#define NEDGES 1600000
#define NB 391          // coarse buckets of 256 nodes: bucket = dst >> 8
#define BSHIFT 8
#define EBLOCKS 391     // (NEDGES + 4095) / 4096
#define GEMM_BLOCKS 1563  // (NNODES + 63) / 64
#define CVT_BLOCKS 96   // (128*128 + 128*64) / 256

typedef _Float16 f16;
typedef _Float16 v4h __attribute__((ext_vector_type(4)));
typedef _Float16 v8h __attribute__((ext_vector_type(8)));
typedef float v4f __attribute__((ext_vector_type(4)));

// ---------------------------------------------------------------------------
// Fused: bucket histogram (blocks 0..EBLOCKS-1) + weight transpose/convert
// (blocks EBLOCKS..EBLOCKS+CVT_BLOCKS-1). Independent work, one launch.
// ---------------------------------------------------------------------------
__global__ __launch_bounds__(256) void hist_cvt(const int* __restrict__ dst,
                                                int* __restrict__ bhist,
                                                const float* __restrict__ W1,
                                                f16* __restrict__ W1t,
                                                const float* __restrict__ W2,
                                                f16* __restrict__ W2t) {
    __shared__ int h[NB];
    if (blockIdx.x >= EBLOCKS) {
        int t = (blockIdx.x - EBLOCKS) * 256 + threadIdx.x;
        if (t < 128 * 128) {
            int k = t >> 7, n = t & 127;
            W1t[n * 128 + k] = (f16)W1[k * 128 + n];
        } else if (t < 128 * 128 + 128 * 64) {
            int u = t - 128 * 128;
            int k = u >> 6, n = u & 63;
            W2t[n * 128 + k] = (f16)W2[k * 64 + n];
        }
        return;
    }
    for (int i = threadIdx.x; i < NB; i += 256) h[i] = 0;
    __syncthreads();
    int base = blockIdx.x * 4096;
    for (int k = 0; k < 16; k++) {
        int e = base + k * 256 + threadIdx.x;
        if (e < NEDGES) atomicAdd(&h[dst[e] >> BSHIFT], 1);
    }
    __syncthreads();
    for (int i = threadIdx.x; i < NB; i += 256)
        if (h[i]) atomicAdd(&bhist[i], h[i]);
}

// Exclusive scan of bucket counts (one block), init cursors.
__global__ void bucket_scan(const int* __restrict__ bhist, int* __restrict__ boff,
                            int* __restrict__ bcur) {
    __shared__ int s[512];
    int tid = threadIdx.x;
    int v = (tid < NB) ? bhist[tid] : 0;
    s[tid] = v;
    __syncthreads();
    for (int off = 1; off < 512; off <<= 1) {
        int t = (tid >= off) ? s[tid - off] : 0;
        __syncthreads();
        s[tid] += t;
        __syncthreads();
    }
    int excl = s[tid] - v;
    if (tid < NB) { boff[tid] = excl; bcur[tid] = excl; }
    if (tid == NB - 1) boff[NB] = excl + v;
}

// ---------------------------------------------------------------------------
// Fused: edge scatter into bucket-contiguous ebuf (blocks 0..EBLOCKS-1) +
// layer-1 MFMA GEMM with inline fp32->f16 A conversion (remaining blocks).
// The two are independent; fusing overlaps the CSR critical path with the
// projection. ebuf entry packed 4B: src | (dst&255)<<24  (src < 2^17).
// ---------------------------------------------------------------------------
__global__ __launch_bounds__(256) void scatter_gemm1(
    const int* __restrict__ src, const int* __restrict__ dst,
    int* __restrict__ bcur, int* __restrict__ ebuf,
    const float* __restrict__ feat, const f16* __restrict__ W1t,
    f16* __restrict__ z1) {
    constexpr int PITCH = 136;
    __shared__ __align__(16) char smem[128 * PITCH * 2];  // 34816 B
    int tid = threadIdx.x;

    if (blockIdx.x < EBLOCKS) {
        int* h = (int*)smem;
        int* base_s = ((int*)smem) + 512;
        for (int i = tid; i < NB; i += 256) h[i] = 0;
        __syncthreads();
        int base = blockIdx.x * 4096;
        int d[16], sv[16];
        for (int k = 0; k < 16; k++) {
            int e = base + k * 256 + tid;
            if (e < NEDGES) {
                d[k] = dst[e];
                sv[k] = src[e];
                atomicAdd(&h[d[k] >> BSHIFT], 1);
            } else {
                d[k] = -1;
            }
        }
        __syncthreads();
        for (int i = tid; i < NB; i += 256) {
            int c = h[i];
            if (c) base_s[i] = atomicAdd(&bcur[i], c);
            h[i] = 0;
        }
        __syncthreads();
        for (int k = 0; k < 16; k++) {
            if (d[k] >= 0) {
                int b = d[k] >> BSHIFT;
                int slot = atomicAdd(&h[b], 1);
                ebuf[base_s[b] + slot] = sv[k] | ((d[k] & 255) << 24);
            }
        }
        return;
    }

    // ---- GEMM-1 branch: z1 = f16(feat) @ W1t^T ----
    f16* wlds = (f16*)smem;
    for (int c = tid; c < 128 * 16; c += 256) {
        int n = c >> 4;
        int kc = c & 15;
        *(v8h*)&wlds[n * PITCH + kc * 8] = *(const v8h*)&W1t[n * 128 + kc * 8];
    }
    __syncthreads();

    int wave = tid >> 6, lane = tid & 63, quad = lane >> 4, l16 = lane & 15;
    int m0 = (blockIdx.x - EBLOCKS) * 64 + wave * 16;
    if (m0 >= NNODES) return;  // NNODES % 16 == 0

    v8h a[4];
    const float* arow = feat + (long)(m0 + l16) * 128 + quad * 8;
#pragma unroll
    for (int kb = 0; kb < 4; kb++) {
        float4 f0 = *(const float4*)(arow + kb * 32);
        float4 f1 = *(const float4*)(arow + kb * 32 + 4);
        v8h t = {(f16)f0.x, (f16)f0.y, (f16)f0.z, (f16)f0.w,
                 (f16)f1.x, (f16)f1.y, (f16)f1.z, (f16)f1.w};
        a[kb] = t;
    }

#pragma unroll
    for (int nt = 0; nt < 8; nt++) {
        v4f acc = {0.f, 0.f, 0.f, 0.f};
        const f16* brow = &wlds[(nt * 16 + l16) * PITCH + quad * 8];
#pragma unroll
        for (int kb = 0; kb < 4; kb++) {
            v8h b = *(const v8h*)(brow + kb * 32);
            acc = __builtin_amdgcn_mfma_f32_16x16x32_f16(a[kb], b, acc, 0, 0, 0);
        }
        int n = nt * 16 + l16;
#pragma unroll
        for (int r = 0; r < 4; r++)
            z1[(long)(m0 + quad * 4 + r) * 128 + n] = (f16)acc[r];
    }
}

// Per-bucket CSR fill + offs computation (LDS count/scan/cursor).
__global__ __launch_bounds__(256) void fill_bucket(const int* __restrict__ ebuf,
                                                   const int* __restrict__ boff,
                                                   int* __restrict__ offs,
                                                   int* __restrict__ csr) {
    __shared__ int lc[256];
    __shared__ int ls[256];
    int b = blockIdx.x;
    int tid = threadIdx.x;
    lc[tid] = 0;
    __syncthreads();
    int ebeg = boff[b], eend = boff[b + 1];
    for (int e = ebeg + tid; e < eend; e += 256)
        atomicAdd(&lc[((unsigned)ebuf[e]) >> 24], 1);
    __syncthreads();
    int cnt = lc[tid];
    ls[tid] = cnt;
    __syncthreads();
    for (int off = 1; off < 256; off <<= 1) {
        int t = (tid >= off) ? ls[tid - off] : 0;
        __syncthreads();
        ls[tid] += t;
        __syncthreads();
    }
    int excl = ls[tid] - cnt;
    int node = (b << BSHIFT) + tid;
    if (node < NNODES) offs[node] = ebeg + excl;
    if (node == NNODES - 1) offs[NNODES] = NEDGES;
    ls[tid] = excl;
    lc[tid] = 0;
    __syncthreads();
    for (int e = ebeg + tid; e < eend; e += 256) {
        int p = ebuf[e];
        int dloc = ((unsigned)p) >> 24;
        int slot = atomicAdd(&lc[dloc], 1);
        csr[ebeg + ls[dloc] + slot] = p & 0xFFFFFF;
    }
}

// ---------------------------------------------------------------------------
// MFMA f16 GEMM (A f16): z2 = h1 @ W2t^T. NOUT=64.
// ---------------------------------------------------------------------------
__global__ __launch_bounds__(256) void gemm2(const f16* __restrict__ A,
                                             const f16* __restrict__ Wt,
                                             f16* __restrict__ out) {
    constexpr int PITCH = 136;
    __shared__ f16 wlds[64 * PITCH];
    int tid = threadIdx.x;
    for (int c = tid; c < 64 * 16; c += 256) {
        int n = c >> 4;
        int kc = c & 15;
        *(v8h*)&wlds[n * PITCH + kc * 8] = *(const v8h*)&Wt[n * 128 + kc * 8];
    }
    __syncthreads();

    int wave = tid >> 6, lane = tid & 63, quad = lane >> 4, l16 = lane & 15;
    int m0 = blockIdx.x * 64 + wave * 16;
    if (m0 >= NNODES) return;

    v8h a[4];
    const f16* arow = A + (long)(m0 + l16) * 128 + quad * 8;
#pragma unroll
    for (int kb = 0; kb < 4; kb++) a[kb] = *(const v8h*)(arow + kb * 32);

#pragma unroll
    for (int nt = 0; nt < 4; nt++) {
        v4f acc = {0.f, 0.f, 0.f, 0.f};
        const f16* brow = &wlds[(nt * 16 + l16) * PITCH + quad * 8];
#pragma unroll
        for (int kb = 0; kb < 4; kb++) {
            v8h b = *(const v8h*)(brow + kb * 32);
            acc = __builtin_amdgcn_mfma_f32_16x16x32_f16(a[kb], b, acc, 0, 0, 0);
        }
        int n = nt * 16 + l16;
#pragma unroll
        for (int r = 0; r < 4; r++)
            out[(long)(m0 + quad * 4 + r) * 64 + n] = (f16)acc[r];
    }
}

// ---------------------------------------------------------------------------
// Gather+normalize, 128-wide f16 rows (layer 1):
//   h1[n] = relu( (Σ z[src] + z[n]) / (deg+1) + b1 )
// One wave/node; half-waves own edges; 16 edges/iter = 8 row-loads in
// flight/lane; packed-f16 tree reduction, fp32 master accumulators.
// ---------------------------------------------------------------------------
__global__ void gather128(const v4h* __restrict__ z, const int* __restrict__ offs,
                          const int* __restrict__ csr, const float* __restrict__ bias,
                          v4h* __restrict__ out) {
    int node = (int)(((long)blockIdx.x * blockDim.x + threadIdx.x) >> 6);
    if (node >= NNODES) return;
    int lane = threadIdx.x & 63;
    int half = lane >> 5;
    int c = lane & 31;

    int beg = offs[node];
    int end = offs[node + 1];

    v4h sv = {0, 0, 0, 0};
    if (half == 0) sv = z[(long)node * 32 + c];  // self (issued early)

    float a0 = 0.f, a1 = 0.f, a2 = 0.f, a3 = 0.f;

    int e = beg;
    for (; e + 15 < end; e += 16) {
        int i0 = csr[e + half];
        int i1 = csr[e + 2 + half];
        int i2 = csr[e + 4 + half];
        int i3 = csr[e + 6 + half];
        int i4 = csr[e + 8 + half];
        int i5 = csr[e + 10 + half];
        int i6 = csr[e + 12 + half];
        int i7 = csr[e + 14 + half];
        v4h u0 = z[(long)i0 * 32 + c];
        v4h u1 = z[(long)i1 * 32 + c];
        v4h u2 = z[(long)i2 * 32 + c];
        v4h u3 = z[(long)i3 * 32 + c];
        v4h u4 = z[(long)i4 * 32 + c];
        v4h u5 = z[(long)i5 * 32 + c];
        v4h u6 = z[(long)i6 * 32 + c];
        v4h u7 = z[(long)i7 * 32 + c];
        v4h s01 = u0 + u1, s23 = u2 + u3, s45 = u4 + u5, s67 = u6 + u7;
        v4h s03 = s01 + s23, s47 = s45 + s67;
        v4h s = s03 + s47;
        a0 += (float)s[0]; a1 += (float)s[1];
        a2 += (float)s[2]; a3 += (float)s[3];
    }
    for (; e + 3 < end; e += 4) {
        int i0 = csr[e + half];
        int i1 = csr[e + 2 + half];
        v4h u0 = z[(long)i0 * 32 + c];
        v4h u1 = z[(long)i1 * 32 + c];
        v4h s = u0 + u1;
        a0 += (float)s[0]; a1 += (float)s[1];
        a2 += (float)s[2]; a3 += (float)s[3];
    }
    for (; e < end; e += 2) {
        int t = e + half;
        if (t < end) {
            v4h u = z[(long)csr[t] * 32 + c];
            a0 += (float)u[0]; a1 += (float)u[1];
            a2 += (float)u[2]; a3 += (float)u[3];
        }
    }
    a0 += (float)sv[0]; a1 += (float)sv[1];
    a2 += (float)sv[2]; a3 += (float)sv[3];

    a0 += __shfl_xor(a0, 32);
    a1 += __shfl_xor(a1, 32);
    a2 += __shfl_xor(a2, 32);
    a3 += __shfl_xor(a3, 32);

    if (half == 0) {
        float inv = 1.0f / (float)(end - beg + 1);
        float4 b = ((const float4*)bias)[c];
        v4h o = {(f16)fmaxf(a0 * inv + b.x, 0.f),
                 (f16)fmaxf(a1 * inv + b.y, 0.f),
                 (f16)fmaxf(a2 * inv + b.z, 0.f),
                 (f16)fmaxf(a3 * inv + b.w, 0.f)};
        out[(long)node * 32 + c] = o;
    }
}

// ---------------------------------------------------------------------------
// Gather+normalize, 64-wide f16 rows (layer 2), fp32 out:
//   out[n] = (Σ z2[src] + z2[n]) / (deg+1) + b2
// 16-lane subgroups; 32 edges/iter = 8 loads in flight; f16 tree reduction.
// ---------------------------------------------------------------------------
__global__ void gather64(const v4h* __restrict__ z, const int* __restrict__ offs,
                         const int* __restrict__ csr, const float* __restrict__ bias,
                         float4* __restrict__ out) {
    int node = (int)(((long)blockIdx.x * blockDim.x + threadIdx.x) >> 6);
    if (node >= NNODES) return;
    int lane = threadIdx.x & 63;
    int sub = lane >> 4;
    int c = lane & 15;

    int beg = offs[node];
    int end = offs[node + 1];

    v4h sv = {0, 0, 0, 0};
    if (sub == 0) sv = z[(long)node * 16 + c];

    float a0 = 0.f, a1 = 0.f, a2 = 0.f, a3 = 0.f;

    int e = beg;
    for (; e + 31 < end; e += 32) {
        int i0 = csr[e + sub];
        int i1 = csr[e + 4 + sub];
        int i2 = csr[e + 8 + sub];
        int i3 = csr[e + 12 + sub];
        int i4 = csr[e + 16 + sub];
        int i5 = csr[e + 20 + sub];
        int i6 = csr[e + 24 + sub];
        int i7 = csr[e + 28 + sub];
        v4h u0 = z[(long)i0 * 16 + c];
        v4h u1 = z[(long)i1 * 16 + c];
        v4h u2 = z[(long)i2 * 16 + c];
        v4h u3 = z[(long)i3 * 16 + c];
        v4h u4 = z[(long)i4 * 16 + c];
        v4h u5 = z[(long)i5 * 16 + c];
        v4h u6 = z[(long)i6 * 16 + c];
        v4h u7 = z[(long)i7 * 16 + c];
        v4h s01 = u0 + u1, s23 = u2 + u3, s45 = u4 + u5, s67 = u6 + u7;
        v4h s03 = s01 + s23, s47 = s45 + s67;
        v4h s = s03 + s47;
        a0 += (float)s[0]; a1 += (float)s[1];
        a2 += (float)s[2]; a3 += (float)s[3];
    }
    for (; e + 7 < end; e += 8) {
        int i0 = csr[e + sub];
        int i1 = csr[e + 4 + sub];
        v4h u0 = z[(long)i0 * 16 + c];
        v4h u1 = z[(long)i1 * 16 + c];
        v4h s = u0 + u1;
        a0 += (float)s[0]; a1 += (float)s[1];
        a2 += (float)s[2]; a3 += (float)s[3];
    }
    for (; e < end; e += 4) {
        int t = e + sub;
        if (t < end) {
            v4h u = z[(long)csr[t] * 16 + c];
            a0 += (float)u[0]; a1 += (float)u[1];
            a2 += (float)u[2]; a3 += (float)u[3];
        }
    }
    a0 += (float)sv[0]; a1 += (float)sv[1];
    a2 += (float)sv[2]; a3 += (float)sv[3];

    a0 += __shfl_xor(a0, 16);  a0 += __shfl_xor(a0, 32);
    a1 += __shfl_xor(a1, 16);  a1 += __shfl_xor(a1, 32);
    a2 += __shfl_xor(a2, 16);  a2 += __shfl_xor(a2, 32);
    a3 += __shfl_xor(a3, 16);  a3 += __shfl_xor(a3, 32);

    if (sub == 0) {
        float inv = 1.0f / (float)(end - beg + 1);
        float4 b = ((const float4*)bias)[c];
        out[(long)node * 16 + c] =
            make_float4(a0 * inv + b.x, a1 * inv + b.y, a2 * inv + b.z, a3 * inv + b.w);
    }
}

extern "C" void kernel_launch(void* const* d_in, const int* in_sizes, int n_in,
                              void* d_out, int out_size, void* d_ws, size_t ws_size,
                              hipStream_t stream) {
    const float* feat = (const float*)d_in[0];
    const float* W1   = (const float*)d_in[1];
    const float* b1   = (const float*)d_in[2];
    const float* W2   = (const float*)d_in[3];
    const float* b2   = (const float*)d_in[4];
    const int*   src  = (const int*)d_in[5];
    const int*   dst  = (const int*)d_in[6];
    float* out = (float*)d_out;

    // Workspace layout:
    //   bhist i32[391]    @ 0x0000000
    //   boff  i32[392]    @ 0x0001000
    //   bcur  i32[391]    @ 0x0002000
    //   offs  i32[100001] @ 0x0003000
    //   csr   i32[1.6M]   @ 0x0070000  (6.4 MB)
    //   ebuf  i32[1.6M]   @ 0x0700000  (6.4 MB)
    //   z1    f16[12.8M]  @ 0x0E00000  (25.6 MB)
    //   h1    f16[12.8M]  @ 0x2700000  (25.6 MB)
    //   z2    f16[6.4M]   @ 0x4000000  (12.8 MB)
    //   W1t   f16[16384]  @ 0x4D00000
    //   W2t   f16[8192]   @ 0x4D10000
    char* ws = (char*)d_ws;
    int* bhist = (int*)(ws + 0x0000000);
    int* boff  = (int*)(ws + 0x0001000);
    int* bcur  = (int*)(ws + 0x0002000);
    int* offs  = (int*)(ws + 0x0003000);
    int* csr   = (int*)(ws + 0x0070000);
    int* ebuf  = (int*)(ws + 0x0700000);
    f16* z1    = (f16*)(ws + 0x0E00000);
    f16* h1    = (f16*)(ws + 0x2700000);
    f16* z2    = (f16*)(ws + 0x4000000);
    f16* W1t   = (f16*)(ws + 0x4D00000);
    f16* W2t   = (f16*)(ws + 0x4D10000);

    hipMemsetAsync(bhist, 0, NB * sizeof(int), stream);

    // bucket histogram + weight prep (fused)
    hist_cvt<<<EBLOCKS + CVT_BLOCKS, 256, 0, stream>>>(dst, bhist, W1, W1t, W2, W2t);
    bucket_scan<<<1, 512, 0, stream>>>(bhist, boff, bcur);

    // edge scatter + layer-1 GEMM (fused, independent halves)
    scatter_gemm1<<<EBLOCKS + GEMM_BLOCKS, 256, 0, stream>>>(src, dst, bcur, ebuf,
                                                             feat, W1t, z1);
    fill_bucket<<<NB, 256, 0, stream>>>(ebuf, boff, offs, csr);

    const int GATHER_BLOCKS = (NNODES * 64 + 255) / 256;  // 25000

    // layer 1 gather (+bias+relu)
    gather128<<<GATHER_BLOCKS, 256, 0, stream>>>((const v4h*)z1, offs, csr, b1,
                                                 (v4h*)h1);
    // layer 2 projection then gather (+bias)
    gemm2<<<GEMM_BLOCKS, 256, 0, stream>>>(h1, W2t, z2);
    gather64<<<GATHER_BLOCKS, 256, 0, stream>>>((const v4h*)z2, offs, csr, b2,
                                                (float4*)out);
}

// Round 8
// 268.735 us; speedup vs baseline: 21.2586x; 1.0357x over previous
//
#include <hip/hip_runtime.h>

#define NNODES 100000
#define NEDGES 1600000
#define BSHIFT 7
#define NB 782            // buckets of 128 nodes: bucket = dst >> 7
#define CAP 2560          // padded per-bucket capacity (mean 2048, +11 sigma)
#define EBLOCKS 391       // edge-scatter blocks (4096 edges each)
#define GEMM_BLOCKS 1563  // (NNODES + 63) / 64

typedef _Float16 f16;
typedef _Float16 v4h __attribute__((ext_vector_type(4)));
typedef _Float16 v8h __attribute__((ext_vector_type(8)));
typedef float v4f __attribute__((ext_vector_type(4)));

// ---------------------------------------------------------------------------
// Init: bucket cursors (bcur[b] = b*CAP) + weight transpose/convert to f16.
// ---------------------------------------------------------------------------
__global__ __launch_bounds__(256) void init_k(int* __restrict__ bcur,
                                              const float* __restrict__ W1,
                                              f16* __restrict__ W1t,
                                              const float* __restrict__ W2,
                                              f16* __restrict__ W2t) {
    int t = blockIdx.x * 256 + threadIdx.x;
    if (t < NB) bcur[t] = t * CAP;
    int u = t - 1024;
    if (u >= 0) {
        if (u < 128 * 128) {
            int k = u >> 7, n = u & 127;
            W1t[n * 128 + k] = (f16)W1[k * 128 + n];
        } else if (u < 128 * 128 + 128 * 64) {
            int v = u - 128 * 128;
            int k = v >> 6, n = v & 63;
            W2t[n * 128 + k] = (f16)W2[k * 64 + n];
        }
    }
}

// ---------------------------------------------------------------------------
// Fused: edge scatter into bucket-padded ebuf (blocks 0..EBLOCKS-1) +
// layer-1 MFMA GEMM with inline fp32->f16 A conversion (remaining blocks).
// ebuf entry packed 4B: src | (dst&127)<<24  (src < 2^17).
// ---------------------------------------------------------------------------
__global__ __launch_bounds__(256) void scatter_gemm1(
    const int* __restrict__ src, const int* __restrict__ dst,
    int* __restrict__ bcur, int* __restrict__ ebuf,
    const float* __restrict__ feat, const f16* __restrict__ W1t,
    f16* __restrict__ z1) {
    constexpr int PITCH = 136;
    __shared__ __align__(16) char smem[128 * PITCH * 2];  // 34816 B
    int tid = threadIdx.x;

    if (blockIdx.x < EBLOCKS) {
        int* h = (int*)smem;
        int* base_s = ((int*)smem) + 1024;
        for (int i = tid; i < NB; i += 256) h[i] = 0;
        __syncthreads();
        int base = blockIdx.x * 4096;
        int d[16], sv[16];
        for (int k = 0; k < 16; k++) {
            int e = base + k * 256 + tid;
            if (e < NEDGES) {
                d[k] = dst[e];
                sv[k] = src[e];
                atomicAdd(&h[d[k] >> BSHIFT], 1);
            } else {
                d[k] = -1;
            }
        }
        __syncthreads();
        for (int i = tid; i < NB; i += 256) {
            int c = h[i];
            if (c) base_s[i] = atomicAdd(&bcur[i], c);
            h[i] = 0;
        }
        __syncthreads();
        for (int k = 0; k < 16; k++) {
            if (d[k] >= 0) {
                int b = d[k] >> BSHIFT;
                int slot = atomicAdd(&h[b], 1);
                ebuf[base_s[b] + slot] = sv[k] | ((d[k] & 127) << 24);
            }
        }
        return;
    }

    // ---- GEMM-1 branch: z1 = f16(feat) @ W1t^T ----
    f16* wlds = (f16*)smem;
    for (int c = tid; c < 128 * 16; c += 256) {
        int n = c >> 4;
        int kc = c & 15;
        *(v8h*)&wlds[n * PITCH + kc * 8] = *(const v8h*)&W1t[n * 128 + kc * 8];
    }
    __syncthreads();

    int wave = tid >> 6, lane = tid & 63, quad = lane >> 4, l16 = lane & 15;
    int m0 = (blockIdx.x - EBLOCKS) * 64 + wave * 16;
    if (m0 >= NNODES) return;  // NNODES % 16 == 0

    v8h a[4];
    const float* arow = feat + (long)(m0 + l16) * 128 + quad * 8;
#pragma unroll
    for (int kb = 0; kb < 4; kb++) {
        float4 f0 = *(const float4*)(arow + kb * 32);
        float4 f1 = *(const float4*)(arow + kb * 32 + 4);
        v8h t = {(f16)f0.x, (f16)f0.y, (f16)f0.z, (f16)f0.w,
                 (f16)f1.x, (f16)f1.y, (f16)f1.z, (f16)f1.w};
        a[kb] = t;
    }

#pragma unroll
    for (int nt = 0; nt < 8; nt++) {
        v4f acc = {0.f, 0.f, 0.f, 0.f};
        const f16* brow = &wlds[(nt * 16 + l16) * PITCH + quad * 8];
#pragma unroll
        for (int kb = 0; kb < 4; kb++) {
            v8h b = *(const v8h*)(brow + kb * 32);
            acc = __builtin_amdgcn_mfma_f32_16x16x32_f16(a[kb], b, acc, 0, 0, 0);
        }
        int n = nt * 16 + l16;
#pragma unroll
        for (int r = 0; r < 4; r++)
            z1[(long)(m0 + quad * 4 + r) * 128 + n] = (f16)acc[r];
    }
}

// ---------------------------------------------------------------------------
// Per-bucket CSR fill (padded layout): count 128 nodes in LDS, scan, write
// begs/ends, place edges via LDS cursors. All writes in a ~10KB window.
// ---------------------------------------------------------------------------
__global__ __launch_bounds__(256) void fill_bucket(const int* __restrict__ ebuf,
                                                   const int* __restrict__ bcur,
                                                   int* __restrict__ begs,
                                                   int* __restrict__ ends,
                                                   int* __restrict__ csr) {
    __shared__ int lc[128];
    __shared__ int ls[256];
    int b = blockIdx.x;
    int tid = threadIdx.x;
    if (tid < 128) lc[tid] = 0;
    __syncthreads();
    int ebeg = b * CAP;
    int eend = bcur[b];  // = b*CAP + bucket count
    for (int e = ebeg + tid; e < eend; e += 256)
        atomicAdd(&lc[((unsigned)ebuf[e]) >> 24], 1);
    __syncthreads();
    int cnt = (tid < 128) ? lc[tid] : 0;
    ls[tid] = cnt;
    __syncthreads();
    for (int off = 1; off < 256; off <<= 1) {
        int t = (tid >= off) ? ls[tid - off] : 0;
        __syncthreads();
        ls[tid] += t;
        __syncthreads();
    }
    int excl = ls[tid] - cnt;
    int node = (b << BSHIFT) + tid;
    if (tid < 128 && node < NNODES) {
        begs[node] = ebeg + excl;
        ends[node] = ebeg + excl + cnt;
    }
    if (tid < 128) { ls[tid] = excl; lc[tid] = 0; }
    __syncthreads();
    for (int e = ebeg + tid; e < eend; e += 256) {
        int p = ebuf[e];
        int dloc = ((unsigned)p) >> 24;
        int slot = atomicAdd(&lc[dloc], 1);
        csr[ebeg + ls[dloc] + slot] = p & 0xFFFFFF;
    }
}

// ---------------------------------------------------------------------------
// Fused layer-1 gather + layer-2 projection. 1024-thread blocks = 16 waves =
// 16 nodes. Each wave gathers its node's z1 rows (half-waves own edges,
// 16 edges/iter, packed-f16 tree reduce, fp32 master acc), computes
// h1 = relu((sum+self)/(deg+1) + b1) into an LDS tile; a 4-wave MFMA epilogue
// then computes z2 = h1 @ W2t^T directly (h1 never touches global memory).
// ---------------------------------------------------------------------------
__global__ __launch_bounds__(1024, 8) void gather128_gemm2(
    const v4h* __restrict__ z,        // z1, rows of 32 v4h
    const int* __restrict__ begs, const int* __restrict__ ends,
    const int* __restrict__ csr,
    const float* __restrict__ b1,     // [128]
    const f16* __restrict__ W2t,      // [64,128]
    f16* __restrict__ z2)             // [NNODES,64]
{
    constexpr int PITCH = 136;
    __shared__ f16 w2lds[64 * PITCH];   // 17408 B
    __shared__ f16 atile[16 * PITCH];   //  4352 B
    int tid = threadIdx.x;

    // stage W2t (1024 threads, exactly 64*16 8-half chunks)
    {
        int n = tid >> 4, kc = tid & 15;
        *(v8h*)&w2lds[n * PITCH + kc * 8] = *(const v8h*)&W2t[n * 128 + kc * 8];
    }

    int wavei = tid >> 6;  // local node 0..15
    int lane = tid & 63;
    int half = lane >> 5;
    int c = lane & 31;
    int node = blockIdx.x * 16 + wavei;  // 6250*16 == NNODES exactly

    int beg = begs[node];
    int end = ends[node];

    v4h svv = {0, 0, 0, 0};
    if (half == 0) svv = z[(long)node * 32 + c];  // self term

    float a0 = 0.f, a1 = 0.f, a2 = 0.f, a3 = 0.f;

    int e = beg;
    for (; e + 15 < end; e += 16) {
        int i0 = csr[e + half];
        int i1 = csr[e + 2 + half];
        int i2 = csr[e + 4 + half];
        int i3 = csr[e + 6 + half];
        int i4 = csr[e + 8 + half];
        int i5 = csr[e + 10 + half];
        int i6 = csr[e + 12 + half];
        int i7 = csr[e + 14 + half];
        v4h u0 = z[(long)i0 * 32 + c];
        v4h u1 = z[(long)i1 * 32 + c];
        v4h u2 = z[(long)i2 * 32 + c];
        v4h u3 = z[(long)i3 * 32 + c];
        v4h u4 = z[(long)i4 * 32 + c];
        v4h u5 = z[(long)i5 * 32 + c];
        v4h u6 = z[(long)i6 * 32 + c];
        v4h u7 = z[(long)i7 * 32 + c];
        v4h s01 = u0 + u1, s23 = u2 + u3, s45 = u4 + u5, s67 = u6 + u7;
        v4h s03 = s01 + s23, s47 = s45 + s67;
        v4h s = s03 + s47;
        a0 += (float)s[0]; a1 += (float)s[1];
        a2 += (float)s[2]; a3 += (float)s[3];
    }
    for (; e + 3 < end; e += 4) {
        int i0 = csr[e + half];
        int i1 = csr[e + 2 + half];
        v4h u0 = z[(long)i0 * 32 + c];
        v4h u1 = z[(long)i1 * 32 + c];
        v4h s = u0 + u1;
        a0 += (float)s[0]; a1 += (float)s[1];
        a2 += (float)s[2]; a3 += (float)s[3];
    }
    for (; e < end; e += 2) {
        int t = e + half;
        if (t < end) {
            v4h u = z[(long)csr[t] * 32 + c];
            a0 += (float)u[0]; a1 += (float)u[1];
            a2 += (float)u[2]; a3 += (float)u[3];
        }
    }
    a0 += (float)svv[0]; a1 += (float)svv[1];
    a2 += (float)svv[2]; a3 += (float)svv[3];

    a0 += __shfl_xor(a0, 32);
    a1 += __shfl_xor(a1, 32);
    a2 += __shfl_xor(a2, 32);
    a3 += __shfl_xor(a3, 32);

    if (half == 0) {
        float inv = 1.0f / (float)(end - beg + 1);
        float4 bb = ((const float4*)b1)[c];
        v4h o = {(f16)fmaxf(a0 * inv + bb.x, 0.f),
                 (f16)fmaxf(a1 * inv + bb.y, 0.f),
                 (f16)fmaxf(a2 * inv + bb.z, 0.f),
                 (f16)fmaxf(a3 * inv + bb.w, 0.f)};
        *(v4h*)&atile[wavei * PITCH + c * 4] = o;
    }
    __syncthreads();

    // ---- epilogue: z2[16 rows] = atile @ W2t^T, waves 0..3 (one n-tile each)
    if (wavei < 4) {
        int quad = lane >> 4, l16 = lane & 15;
        const f16* arow = &atile[l16 * PITCH + quad * 8];
        const f16* brow = &w2lds[(wavei * 16 + l16) * PITCH + quad * 8];
        v4f acc = {0.f, 0.f, 0.f, 0.f};
#pragma unroll
        for (int kb = 0; kb < 4; kb++) {
            v8h av = *(const v8h*)(arow + kb * 32);
            v8h bv = *(const v8h*)(brow + kb * 32);
            acc = __builtin_amdgcn_mfma_f32_16x16x32_f16(av, bv, acc, 0, 0, 0);
        }
        int n = wavei * 16 + l16;
        int m0 = blockIdx.x * 16;
#pragma unroll
        for (int r = 0; r < 4; r++)
            z2[(long)(m0 + quad * 4 + r) * 64 + n] = (f16)acc[r];
    }
}

// ---------------------------------------------------------------------------
// Layer-2 gather+normalize over 64-wide f16 rows, fp32 out:
//   out[n] = (Σ z2[src] + z2[n]) / (deg+1) + b2
// 16-lane subgroups; 32 edges/iter = 8 loads in flight; f16 tree reduction.
// ---------------------------------------------------------------------------
__global__ void gather64(const v4h* __restrict__ z, const int* __restrict__ begs,
                         const int* __restrict__ ends, const int* __restrict__ csr,
                         const float* __restrict__ bias, float4* __restrict__ out) {
    int node = (int)(((long)blockIdx.x * blockDim.x + threadIdx.x) >> 6);
    if (node >= NNODES) return;
    int lane = threadIdx.x & 63;
    int sub = lane >> 4;
    int c = lane & 15;

    int beg = begs[node];
    int end = ends[node];

    v4h svv = {0, 0, 0, 0};
    if (sub == 0) svv = z[(long)node * 16 + c];

    float a0 = 0.f, a1 = 0.f, a2 = 0.f, a3 = 0.f;

    int e = beg;
    for (; e + 31 < end; e += 32) {
        int i0 = csr[e + sub];
        int i1 = csr[e + 4 + sub];
        int i2 = csr[e + 8 + sub];
        int i3 = csr[e + 12 + sub];
        int i4 = csr[e + 16 + sub];
        int i5 = csr[e + 20 + sub];
        int i6 = csr[e + 24 + sub];
        int i7 = csr[e + 28 + sub];
        v4h u0 = z[(long)i0 * 16 + c];
        v4h u1 = z[(long)i1 * 16 + c];
        v4h u2 = z[(long)i2 * 16 + c];
        v4h u3 = z[(long)i3 * 16 + c];
        v4h u4 = z[(long)i4 * 16 + c];
        v4h u5 = z[(long)i5 * 16 + c];
        v4h u6 = z[(long)i6 * 16 + c];
        v4h u7 = z[(long)i7 * 16 + c];
        v4h s01 = u0 + u1, s23 = u2 + u3, s45 = u4 + u5, s67 = u6 + u7;
        v4h s03 = s01 + s23, s47 = s45 + s67;
        v4h s = s03 + s47;
        a0 += (float)s[0]; a1 += (float)s[1];
        a2 += (float)s[2]; a3 += (float)s[3];
    }
    for (; e + 7 < end; e += 8) {
        int i0 = csr[e + sub];
        int i1 = csr[e + 4 + sub];
        v4h u0 = z[(long)i0 * 16 + c];
        v4h u1 = z[(long)i1 * 16 + c];
        v4h s = u0 + u1;
        a0 += (float)s[0]; a1 += (float)s[1];
        a2 += (float)s[2]; a3 += (float)s[3];
    }
    for (; e < end; e += 4) {
        int t = e + sub;
        if (t < end) {
            v4h u = z[(long)csr[t] * 16 + c];
            a0 += (float)u[0]; a1 += (float)u[1];
            a2 += (float)u[2]; a3 += (float)u[3];
        }
    }
    a0 += (float)svv[0]; a1 += (float)svv[1];
    a2 += (float)svv[2]; a3 += (float)svv[3];

    a0 += __shfl_xor(a0, 16);  a0 += __shfl_xor(a0, 32);
    a1 += __shfl_xor(a1, 16);  a1 += __shfl_xor(a1, 32);
    a2 += __shfl_xor(a2, 16);  a2 += __shfl_xor(a2, 32);
    a3 += __shfl_xor(a3, 16);  a3 += __shfl_xor(a3, 32);

    if (sub == 0) {
        float inv = 1.0f / (float)(end - beg + 1);
        float4 b = ((const float4*)bias)[c];
        out[(long)node * 16 + c] =
            make_float4(a0 * inv + b.x, a1 * inv + b.y, a2 * inv + b.z, a3 * inv + b.w);
    }
}

extern "C" void kernel_launch(void* const* d_in, const int* in_sizes, int n_in,
                              void* d_out, int out_size, void* d_ws, size_t ws_size,
                              hipStream_t stream) {
    const float* feat = (const float*)d_in[0];
    const float* W1   = (const float*)d_in[1];
    const float* b1   = (const float*)d_in[2];
    const float* W2   = (const float*)d_in[3];
    const float* b2   = (const float*)d_in[4];
    const int*   src  = (const int*)d_in[5];
    const int*   dst  = (const int*)d_in[6];
    float* out = (float*)d_out;

    // Workspace layout:
    //   bcur i32[782]       @ 0x0000000
    //   begs i32[100000]    @ 0x0001000  (400000 B)
    //   ends i32[100000]    @ 0x0063000  (400000 B)
    //   csr  i32[NB*CAP=2001920] @ 0x00C5000  (8.0 MB, bucket-padded)
    //   ebuf i32[NB*CAP]    @ 0x0870000  (8.0 MB, bucket-padded)
    //   z1   f16[12.8M]     @ 0x1100000  (25.6 MB)
    //   z2   f16[6.4M]      @ 0x2A00000  (12.8 MB)
    //   W1t  f16[16384]     @ 0x3700000
    //   W2t  f16[8192]      @ 0x3710000
    char* ws = (char*)d_ws;
    int* bcur = (int*)(ws + 0x0000000);
    int* begs = (int*)(ws + 0x0001000);
    int* ends = (int*)(ws + 0x0063000);
    int* csr  = (int*)(ws + 0x00C5000);
    int* ebuf = (int*)(ws + 0x0870000);
    f16* z1   = (f16*)(ws + 0x1100000);
    f16* z2   = (f16*)(ws + 0x2A00000);
    f16* W1t  = (f16*)(ws + 0x3700000);
    f16* W2t  = (f16*)(ws + 0x3710000);

    // 1. init cursors + weight prep (no memsets needed anywhere)
    init_k<<<100, 256, 0, stream>>>(bcur, W1, W1t, W2, W2t);

    // 2. edge scatter into padded buckets + layer-1 GEMM (fused)
    scatter_gemm1<<<EBLOCKS + GEMM_BLOCKS, 256, 0, stream>>>(src, dst, bcur, ebuf,
                                                             feat, W1t, z1);

    // 3. per-bucket CSR fill + per-node beg/end
    fill_bucket<<<NB, 256, 0, stream>>>(ebuf, bcur, begs, ends, csr);

    // 4. layer-1 gather (+bias+relu) fused with layer-2 projection
    gather128_gemm2<<<NNODES / 16, 1024, 0, stream>>>((const v4h*)z1, begs, ends,
                                                      csr, b1, W2t, z2);

    // 5. layer-2 gather (+bias) -> output
    gather64<<<(NNODES * 64 + 255) / 256, 256, 0, stream>>>((const v4h*)z2, begs,
                                                            ends, csr, b2,
                                                            (float4*)out);
}